// Round 10
// baseline (554.465 us; speedup 1.0000x reference)
//
#include <hip/hip_runtime.h>

typedef __attribute__((ext_vector_type(8))) short bf16x8;
typedef __attribute__((ext_vector_type(4))) float f32x4;

#define LPAD 2432
#define LKV  2382
#define NSEQ 2304
#define CDIM 512
#define LPROWS (4 * NSEQ * 8)  // l-partial entries per split

__device__ __forceinline__ unsigned short f2bf(float f) {
  unsigned int u = __builtin_bit_cast(unsigned int, f);
  u += 0x7fffu + ((u >> 16) & 1u);
  return (unsigned short)(u >> 16);
}
__device__ __forceinline__ float bf2f(unsigned short s) {
  unsigned int u = ((unsigned int)s) << 16;
  return __builtin_bit_cast(float, u);
}
__device__ __forceinline__ f32x4 MFMA(bf16x8 a, bf16x8 b, f32x4 c) {
  return __builtin_amdgcn_mfma_f32_16x16x32_bf16(a, b, c, 0, 0, 0);
}
__device__ __forceinline__ void stage16(const unsigned short* g, unsigned short* l) {
  __builtin_amdgcn_global_load_lds((const __attribute__((address_space(1))) void*)g,
                                   (__attribute__((address_space(3))) void*)l, 16, 0, 0);
}
__device__ __forceinline__ unsigned int cvtpk(float a, float b) {
  unsigned int r;
  asm("v_cvt_pk_bf16_f32 %0, %1, %2" : "=v"(r) : "v"(a), "v"(b));
  return r;
}
// interleaved V^T column position within each 32-chunk
__device__ __forceinline__ int Fj(int j) {
  return (j & ~31) | ((j & 15) << 1) | ((j >> 4) & 1);
}

// ---------------- weight transpose + bf16 convert ----------------
__global__ void k_prep(const float* __restrict__ Wq, const float* __restrict__ Wkv,
                       const float* __restrict__ Wctx, const float* __restrict__ Wout,
                       unsigned short* __restrict__ WqT, unsigned short* __restrict__ WkvT,
                       unsigned short* __restrict__ WctxT, unsigned short* __restrict__ WoutT) {
  int idx = blockIdx.x * 256 + threadIdx.x;
  if (idx < 262144) {
    int n = idx >> 9, k = idx & 511;
    WqT[idx] = f2bf(Wq[k * 512 + n]);
  } else if ((idx -= 262144) < 65536) {
    int n = idx >> 9, k = idx & 511;
    WkvT[idx] = f2bf(Wkv[k * 128 + n]);
  } else if ((idx -= 65536) < 98304) {
    int n = idx / 768, k = idx - n * 768;
    WctxT[idx] = f2bf(Wctx[k * 128 + n]);
  } else {
    idx -= 98304;
    int n = idx >> 9, k = idx & 511;
    WoutT[idx] = f2bf(Wout[k * 512 + n]);
  }
}

// ---------------- LN over C of x (B,C,N) -> xn bf16 (B*N, C) ----------------
__global__ void k_ln1(const float* __restrict__ x, const float* __restrict__ g,
                      unsigned short* __restrict__ xn) {
  int b = blockIdx.y;
  int i0 = blockIdx.x * 32;
  int t = threadIdx.x;
  int ii = t & 31, ci = t >> 5;
  const float* xb = x + (size_t)b * CDIM * NSEQ;
  float s = 0.f, s2 = 0.f;
  for (int c = ci; c < CDIM; c += 8) {
    float v = xb[(size_t)c * NSEQ + i0 + ii];
    s += v; s2 += v * v;
  }
  __shared__ float ls[8][32], ls2[8][32];
  __shared__ float lmu[32], lrs[32];
  ls[ci][ii] = s; ls2[ci][ii] = s2;
  __syncthreads();
  if (t < 32) {
    float a = 0.f, a2 = 0.f;
    for (int q = 0; q < 8; q++) { a += ls[q][t]; a2 += ls2[q][t]; }
    float mu = a * (1.0f / 512.0f);
    float var = a2 * (1.0f / 512.0f) - mu * mu;
    lmu[t] = mu; lrs[t] = rsqrtf(var + 1e-5f);
  }
  __syncthreads();
  float mu = lmu[ii], rs = lrs[ii];
  unsigned short* xrow = xn + (size_t)(b * NSEQ + i0 + ii) * CDIM;
  for (int c = ci; c < CDIM; c += 8) {
    float v = xb[(size_t)c * NSEQ + i0 + ii];
    xrow[c] = f2bf((v - mu) * rs * g[c]);
  }
}

// ---------------- context LN + projection; null row + zero pads ----------
__global__ void k_ctx(const float* __restrict__ ctx, const float* __restrict__ g,
                      const float* __restrict__ be, const unsigned short* __restrict__ WctxT,
                      const float* __restrict__ bctx, const float* __restrict__ null_kv,
                      unsigned short* __restrict__ kb, unsigned short* __restrict__ vt) {
  int b = blockIdx.y, j = blockIdx.x;
  int t = threadIdx.x;
  if (j == 77) {
    if (t < 64) kb[((size_t)b * LPAD + 77) * 64 + t] = f2bf(null_kv[t]);
    else vt[((size_t)b * 64 + (t - 64)) * LPAD + Fj(77)] = f2bf(null_kv[64 + (t - 64)]);
    return;
  }
  if (j > 77) {
    int jj = LKV + (j - 78);
    if (t < 64) kb[((size_t)b * LPAD + jj) * 64 + t] = 0;
    else vt[((size_t)b * 64 + (t - 64)) * LPAD + Fj(jj)] = 0;
    return;
  }
  __shared__ float row[768];
  __shared__ float red[4];
  const float* src = ctx + (size_t)(b * 77 + j) * 768;
  float s = 0.f, s2 = 0.f;
  for (int k = t; k < 768; k += 128) {
    float v = src[k];
    row[k] = v; s += v; s2 += v * v;
  }
  for (int o = 32; o; o >>= 1) { s += __shfl_xor(s, o); s2 += __shfl_xor(s2, o); }
  if ((t & 63) == 0) { red[(t >> 6) * 2] = s; red[(t >> 6) * 2 + 1] = s2; }
  __syncthreads();
  float S = red[0] + red[2], S2 = red[1] + red[3];
  float mu = S * (1.0f / 768.0f);
  float rs = rsqrtf(S2 * (1.0f / 768.0f) - mu * mu + 1e-5f);
  __syncthreads();
  for (int k = t; k < 768; k += 128) row[k] = (row[k] - mu) * rs * g[k] + be[k];
  __syncthreads();
  const uint4* w4 = reinterpret_cast<const uint4*>(WctxT + (size_t)t * 768);
  float acc = 0.f;
  for (int k8 = 0; k8 < 96; k8++) {
    union { uint4 u; unsigned short s[8]; } wv;
    wv.u = w4[k8];
#pragma unroll
    for (int e = 0; e < 8; e++) acc += row[k8 * 8 + e] * bf2f(wv.s[e]);
  }
  acc += bctx[t];
  if (t < 64) kb[((size_t)b * LPAD + j) * 64 + t] = f2bf(acc);
  else vt[((size_t)b * 64 + (t - 64)) * LPAD + Fj(j)] = f2bf(acc);
}

// ---------------- MFMA GEMM ----------------
template <int MODE>
__global__ __launch_bounds__(256, 1) void k_gemm(
    const unsigned short* __restrict__ A, const unsigned short* __restrict__ BT0,
    const unsigned short* __restrict__ BT1, unsigned short* __restrict__ out_q,
    unsigned short* __restrict__ out_k, unsigned short* __restrict__ out_vt,
    float* __restrict__ out_proj) {
  int m0 = blockIdx.x * 128, n0 = blockIdx.y * 128;
  int t = threadIdx.x;
  int lane = t & 63, w = t >> 6;
  int wm = w >> 1, wn = w & 1;
  int G = lane >> 4, li = lane & 15;
  __shared__ unsigned short Al[128][72];
  __shared__ unsigned short Bl[128][72];
  const unsigned short* BT = (MODE == 0 && n0 >= 512) ? BT1 : BT0;
  int bn0 = (MODE == 0 && n0 >= 512) ? n0 - 512 : n0;
  f32x4 zero = {0.f, 0.f, 0.f, 0.f};
  f32x4 acc[4][4];
#pragma unroll
  for (int a = 0; a < 4; a++)
#pragma unroll
    for (int c = 0; c < 4; c++) acc[a][c] = zero;
  int sr = t >> 1, sc = (t & 1) * 32;
  for (int k0 = 0; k0 < 512; k0 += 64) {
    const uint4* sA = reinterpret_cast<const uint4*>(A + (size_t)(m0 + sr) * 512 + k0 + sc);
    const uint4* sB = reinterpret_cast<const uint4*>(BT + (size_t)(bn0 + sr) * 512 + k0 + sc);
    uint4 a0 = sA[0], a1 = sA[1], a2 = sA[2], a3 = sA[3];
    uint4 b0 = sB[0], b1 = sB[1], b2 = sB[2], b3 = sB[3];
    uint4* dA = reinterpret_cast<uint4*>(&Al[sr][sc]);
    uint4* dB = reinterpret_cast<uint4*>(&Bl[sr][sc]);
    dA[0] = a0; dA[1] = a1; dA[2] = a2; dA[3] = a3;
    dB[0] = b0; dB[1] = b1; dB[2] = b2; dB[3] = b3;
    __syncthreads();
#pragma unroll
    for (int ks = 0; ks < 2; ks++) {
      bf16x8 af[4], bfr[4];
#pragma unroll
      for (int f = 0; f < 4; f++) {
        af[f] = *reinterpret_cast<const bf16x8*>(&Al[wm * 64 + f * 16 + li][ks * 32 + G * 8]);
        bfr[f] = *reinterpret_cast<const bf16x8*>(&Bl[wn * 64 + f * 16 + li][ks * 32 + G * 8]);
      }
#pragma unroll
      for (int fm = 0; fm < 4; fm++)
#pragma unroll
        for (int fn = 0; fn < 4; fn++)
          acc[fm][fn] = MFMA(af[fm], bfr[fn], acc[fm][fn]);
    }
    __syncthreads();
  }
#pragma unroll
  for (int fm = 0; fm < 4; fm++)
#pragma unroll
    for (int fn = 0; fn < 4; fn++)
#pragma unroll
      for (int r = 0; r < 4; r++) {
        int row = m0 + wm * 64 + fm * 16 + G * 4 + r;
        int col = n0 + wn * 64 + fn * 16 + li;
        float v = acc[fm][fn][r];
        if (MODE == 0) {
          int b = row / NSEQ, i = row - b * NSEQ;
          // q pre-scaled by 1/sqrt(dh) * log2(e): softmax runs in exp2 domain
          if (col < 512) out_q[(size_t)row * 512 + col] = f2bf(v * 0.18033688011112042f);
          else if (col < 576) out_k[((size_t)b * LPAD + 78 + i) * 64 + (col - 512)] = f2bf(v);
          else out_vt[((size_t)b * 64 + (col - 576)) * LPAD + Fj(78 + i)] = f2bf(v);
        } else {
          out_proj[(size_t)row * 512 + col] = v;
        }
      }
}

// ---------------- flash attention: 2-way KV split, 8 waves = 8 heads --------
// Block = 512 threads; wave w owns head w; one K/V staging serves all 8 heads.
// no-max exp2 softmax -> split partials combine by pure addition.
// K tile [64j][64d]; V^T tile [64d][64 interleaved-j] (Fj layout) staged via
// global_load_lds (ONE stage16 per thread per tile for K and V: 512 lanes x
// 16B = 8KB tile), source-side XOR swizzle; reads apply same XOR.
// Double-buffer parity is LOCAL (u&1).
__global__ __launch_bounds__(512, 4) void k_attn(
    const unsigned short* __restrict__ q, const unsigned short* __restrict__ kbuf,
    const unsigned short* __restrict__ vt, unsigned short* __restrict__ pO0,
    unsigned short* __restrict__ pO1, float* __restrict__ lp) {
  int bx = blockIdx.x;
  int it = bx >> 1, sp = bx & 1;
  int b = blockIdx.z;
  int i0 = it * 32;
  int t = threadIdx.x;
  int w = t >> 6, lane = t & 63;
  int G = lane >> 4, li = lane & 15, li7 = lane & 7;
  int h = w;  // wave = head

  __shared__ __align__(16) unsigned short Kl[2][4096];
  __shared__ __align__(16) unsigned short Vl[2][4096];

  int r1 = t >> 3;                       // 0..63 (full tile row)
  int c1 = ((t & 7) ^ (r1 & 7)) * 8;     // swizzled 16B-granule column

  const unsigned short* kbase = kbuf + (size_t)b * LPAD * 64;
  const unsigned short* vbase = vt + (size_t)b * 64 * LPAD;

  bf16x8 qf[2][2];
#pragma unroll
  for (int fi = 0; fi < 2; fi++)
#pragma unroll
    for (int ks = 0; ks < 2; ks++)
      qf[fi][ks] = *reinterpret_cast<const bf16x8*>(
          q + (size_t)(b * NSEQ + i0 + fi * 16 + li) * CDIM + h * 64 + ks * 32 + G * 8);

  int jt0 = sp * 19;

  // stage first tile of this split into buffer [0]
  {
    int j0 = jt0 * 64;
    stage16(kbase + (size_t)(j0 + r1) * 64 + c1, &Kl[0][w * 512]);
    stage16(vbase + (size_t)r1 * LPAD + j0 + c1, &Vl[0][w * 512]);
  }

  f32x4 zero = {0.f, 0.f, 0.f, 0.f};
  f32x4 OT[4][2];  // [fd][fi]; row d = fd*16+G*4+r, col i = fi*16+li
#pragma unroll
  for (int fd = 0; fd < 4; fd++)
#pragma unroll
    for (int fi = 0; fi < 2; fi++) OT[fd][fi] = zero;
  float l_[2] = {0.f, 0.f};

  __syncthreads();

#pragma unroll 2
  for (int u = 0; u < 19; u++) {
    int jt = jt0 + u;
    int cur = u & 1, nxt = cur ^ 1;  // LOCAL parity
    int j0 = jt * 64;
    if (u + 1 < 19) {
      int j1 = j0 + 64;
      stage16(kbase + (size_t)(j1 + r1) * 64 + c1, &Kl[nxt][w * 512]);
      stage16(vbase + (size_t)r1 * LPAD + j1 + c1, &Vl[nxt][w * 512]);
    }
    const char* Kc = (const char*)Kl[cur];
    const char* Vc = (const char*)Vl[cur];

    f32x4 S[4][2];
#pragma unroll
    for (int fj = 0; fj < 4; fj++) { S[fj][0] = zero; S[fj][1] = zero; }
#pragma unroll
    for (int ks = 0; ks < 2; ks++) {
      bf16x8 kf[4];
#pragma unroll
      for (int fj = 0; fj < 4; fj++)
        kf[fj] = *reinterpret_cast<const bf16x8*>(
            Kc + ((((fj * 16 + li) * 8) + ((ks * 4 + G) ^ li7)) << 4));
#pragma unroll
      for (int fj = 0; fj < 4; fj++)
#pragma unroll
        for (int fi = 0; fi < 2; fi++)
          S[fj][fi] = MFMA(kf[fj], qf[fi][ks], S[fj][fi]);
    }
    if (j0 + 64 > LKV) {
#pragma unroll
      for (int fj = 0; fj < 4; fj++)
#pragma unroll
        for (int r = 0; r < 4; r++) {
          int jg = j0 + fj * 16 + G * 4 + r;
          if (jg >= LKV) { S[fj][0][r] = -1e30f; S[fj][1][r] = -1e30f; }
        }
    }
    // no-max softmax: e = exp2(S); pack pf in interleaved-j bijection:
    // B k-slot (G,E) <-> j = ks*32 + (E&1)*16 + G*4 + (E>>1)
    bf16x8 pf[2][2];
#pragma unroll
    for (int fi = 0; fi < 2; fi++) {
      float e[4][4];
#pragma unroll
      for (int fj = 0; fj < 4; fj++)
#pragma unroll
        for (int r = 0; r < 4; r++) e[fj][r] = __builtin_exp2f(S[fj][fi][r]);
      float s0 = (e[0][0] + e[0][1]) + (e[0][2] + e[0][3]);
      float s1 = (e[1][0] + e[1][1]) + (e[1][2] + e[1][3]);
      float s2 = (e[2][0] + e[2][1]) + (e[2][2] + e[2][3]);
      float s3 = (e[3][0] + e[3][1]) + (e[3][2] + e[3][3]);
      l_[fi] += (s0 + s1) + (s2 + s3);
#pragma unroll
      for (int ks = 0; ks < 2; ks++) {
        union { unsigned int w4[4]; bf16x8 v; } u2;
#pragma unroll
        for (int m = 0; m < 4; m++) u2.w4[m] = cvtpk(e[2 * ks][m], e[2 * ks + 1][m]);
        pf[fi][ks] = u2.v;
      }
    }
    // PV from LDS V^T (interleaved layout): one b128 per (ks, fd)
#pragma unroll
    for (int ks = 0; ks < 2; ks++) {
#pragma unroll
      for (int fd = 0; fd < 4; fd++) {
        bf16x8 uv = *reinterpret_cast<const bf16x8*>(
            Vc + (((fd * 16 + li) * 8 + ((ks * 4 + G) ^ li7)) << 4));
#pragma unroll
        for (int fi = 0; fi < 2; fi++) OT[fd][fi] = MFMA(uv, pf[fi][ks], OT[fd][fi]);
      }
    }
    __syncthreads();
  }

  // write unnormalized partials + l partials
  unsigned short* pO = sp ? pO1 : pO0;
#pragma unroll
  for (int fi = 0; fi < 2; fi++) {
    l_[fi] += __shfl_xor(l_[fi], 16);
    l_[fi] += __shfl_xor(l_[fi], 32);
    int row = b * NSEQ + i0 + fi * 16 + li;
    if (G == 0) lp[sp * LPROWS + row * 8 + h] = l_[fi];
#pragma unroll
    for (int fd = 0; fd < 4; fd++) {
      union { unsigned int w2[2]; uint2 u2; } pk;
      pk.w2[0] = cvtpk(OT[fd][fi][0], OT[fd][fi][1]);
      pk.w2[1] = cvtpk(OT[fd][fi][2], OT[fd][fi][3]);
      *reinterpret_cast<uint2*>(pO + (size_t)row * CDIM + h * 64 + fd * 16 + G * 4) = pk.u2;
    }
  }
}

// ---------------- merge the two KV-split partials ----------------
// out (in place over pO0) = (O0 + O1) / (l0 + l1), bf16
__global__ void k_merge(unsigned short* __restrict__ pO0,
                        const unsigned short* __restrict__ pO1,
                        const float* __restrict__ lp) {
  int c = blockIdx.x * 256 + threadIdx.x;  // 16B chunk index (8 bf16)
  size_t base = (size_t)c * 8;
  int row = (int)(base >> 9);
  int h = (int)((base >> 6) & 7);
  float l = lp[row * 8 + h] + lp[LPROWS + row * 8 + h];
  float inv = 1.0f / l;
  union { uint4 u; unsigned short s[8]; } a, bq, o;
  a.u = *reinterpret_cast<const uint4*>(pO0 + base);
  bq.u = *reinterpret_cast<const uint4*>(pO1 + base);
  unsigned int* ow = reinterpret_cast<unsigned int*>(&o.u);
#pragma unroll
  for (int m = 0; m < 4; m++) {
    float v0 = (bf2f(a.s[2 * m]) + bf2f(bq.s[2 * m])) * inv;
    float v1 = (bf2f(a.s[2 * m + 1]) + bf2f(bq.s[2 * m + 1])) * inv;
    ow[m] = cvtpk(v0, v1);
  }
  *reinterpret_cast<uint4*>(pO0 + base) = o.u;
}

// ---------------- per-row LN stats of proj (coalesced) ----------------
__global__ void k_stats(const float* __restrict__ proj, float* __restrict__ musig) {
  int w = threadIdx.x >> 6, lane = threadIdx.x & 63;
  int row = blockIdx.x * 4 + w;
  const float* pr = proj + (size_t)row * CDIM;
  const float4* p4 = reinterpret_cast<const float4*>(pr + lane * 8);
  float4 a = p4[0], bq = p4[1];
  float s = a.x + a.y + a.z + a.w + bq.x + bq.y + bq.z + bq.w;
  float s2 = a.x * a.x + a.y * a.y + a.z * a.z + a.w * a.w +
             bq.x * bq.x + bq.y * bq.y + bq.z * bq.z + bq.w * bq.w;
  for (int o = 32; o; o >>= 1) { s += __shfl_xor(s, o); s2 += __shfl_xor(s2, o); }
  if (lane == 0) {
    float mu = s * (1.0f / 512.0f);
    float var = s2 * (1.0f / 512.0f) - mu * mu;
    musig[row] = mu;
    musig[4 * NSEQ + row] = rsqrtf(var + 1e-5f);
  }
}

// ---------------- final LN + residual, LDS-transposed, fully coalesced ------
__global__ void k_final2(const float* __restrict__ proj, const float* __restrict__ musig,
                         const float* __restrict__ g, const float* __restrict__ x,
                         float* __restrict__ y) {
  int i0 = blockIdx.x * 32, c0 = blockIdx.y * 64, b = blockIdx.z;
  int t = threadIdx.x;
  __shared__ float lds[32][65];
  {
    int il = t >> 3, cB = (t & 7) * 8;
    const float4* src = reinterpret_cast<const float4*>(
        proj + (size_t)(b * NSEQ + i0 + il) * CDIM + c0 + cB);
    float4 v0 = src[0], v1 = src[1];
    *reinterpret_cast<float4*>(&lds[il][cB]) = v0;
    *reinterpret_cast<float4*>(&lds[il][cB + 4]) = v1;
  }
  __syncthreads();
  int ii = t & 31, cg = t >> 5;
  float mu = musig[b * NSEQ + i0 + ii];
  float rs = musig[4 * NSEQ + b * NSEQ + i0 + ii];
  const float* xb = x + (size_t)b * CDIM * NSEQ;
  float* yb = y + (size_t)b * CDIM * NSEQ;
#pragma unroll
  for (int cc = 0; cc < 8; cc++) {
    int cl = cg * 8 + cc;
    int c = c0 + cl;
    float v = lds[ii][cl];
    yb[(size_t)c * NSEQ + i0 + ii] = xb[(size_t)c * NSEQ + i0 + ii] + (v - mu) * rs * g[c];
  }
}

extern "C" void kernel_launch(void* const* d_in, const int* in_sizes, int n_in,
                              void* d_out, int out_size, void* d_ws, size_t ws_size,
                              hipStream_t stream) {
  const float* x       = (const float*)d_in[0];
  const float* context = (const float*)d_in[1];
  const float* ngamma  = (const float*)d_in[2];
  const float* null_kv = (const float*)d_in[3];
  const float* Wq      = (const float*)d_in[4];
  const float* Wkv     = (const float*)d_in[5];
  const float* clng    = (const float*)d_in[6];
  const float* clnb    = (const float*)d_in[7];
  const float* Wctx    = (const float*)d_in[8];
  const float* bctx    = (const float*)d_in[9];
  const float* Wout    = (const float*)d_in[10];
  const float* olng    = (const float*)d_in[11];
  float* y = (float*)d_out;
  char* ws = (char*)d_ws;

  unsigned short* xn    = (unsigned short*)(ws);              // 9437184 B (also pO1 during attn)
  unsigned short* qb    = (unsigned short*)(ws + 9437184);    // 9437184 B
  float* proj           = (float*)(ws);                       // aliases xn+qb (dead by then)
  unsigned short* aoutb = (unsigned short*)(ws + 18874368);   // 9437184 B (pO0 -> merged)
  float* musig          = (float*)(ws + 18874368);            // aliases aoutb (dead after gemm1)
  unsigned short* kb    = (unsigned short*)(ws + 28311552);   // 1245184 B
  unsigned short* vtb   = (unsigned short*)(ws + 29556736);   // 1245184 B
  unsigned short* WqT   = (unsigned short*)(ws + 30801920);   // 524288 B
  unsigned short* WkvT  = (unsigned short*)(ws + 31326208);   // 131072 B
  unsigned short* WctxT = (unsigned short*)(ws + 31457280);   // 196608 B
  unsigned short* WoutT = (unsigned short*)(ws + 31653888);   // 524288 B
  // l-partials (589824 B) overlay WqT+WkvT (655360 B) — dead after k_gemm<0>
  float* lpart          = (float*)(ws + 30801920);

  k_prep<<<dim3(2688), dim3(256), 0, stream>>>(Wq, Wkv, Wctx, Wout, WqT, WkvT, WctxT, WoutT);
  k_ln1<<<dim3(72, 4), dim3(256), 0, stream>>>(x, ngamma, xn);
  k_ctx<<<dim3(128, 4), dim3(128), 0, stream>>>(context, clng, clnb, WctxT, bctx, null_kv, kb, vtb);
  k_gemm<0><<<dim3(72, 5), dim3(256), 0, stream>>>(xn, WqT, WkvT, qb, kb, vtb, nullptr);
  k_attn<<<dim3(144, 1, 4), dim3(512), 0, stream>>>(qb, kb, vtb, aoutb, xn, lpart);
  k_merge<<<dim3(2304), dim3(256), 0, stream>>>(aoutb, xn, lpart);
  k_gemm<1><<<dim3(72, 4), dim3(256), 0, stream>>>(aoutb, WoutT, nullptr, nullptr, nullptr, nullptr, proj);
  k_stats<<<dim3(2304), dim3(256), 0, stream>>>(proj, musig);
  k_final2<<<dim3(72, 8, 4), dim3(256), 0, stream>>>(proj, musig, olng, x, y);
}

// Round 11
// 206.662 us; speedup vs baseline: 2.6830x; 2.6830x over previous
//
#include <hip/hip_runtime.h>

typedef __attribute__((ext_vector_type(8))) short bf16x8;
typedef __attribute__((ext_vector_type(4))) float f32x4;

#define LPAD 2432
#define LKV  2382
#define NSEQ 2304
#define CDIM 512
#define LPROWS (4 * NSEQ * 8)  // l-partial entries per split

__device__ __forceinline__ unsigned short f2bf(float f) {
  unsigned int u = __builtin_bit_cast(unsigned int, f);
  u += 0x7fffu + ((u >> 16) & 1u);
  return (unsigned short)(u >> 16);
}
__device__ __forceinline__ float bf2f(unsigned short s) {
  unsigned int u = ((unsigned int)s) << 16;
  return __builtin_bit_cast(float, u);
}
__device__ __forceinline__ f32x4 MFMA(bf16x8 a, bf16x8 b, f32x4 c) {
  return __builtin_amdgcn_mfma_f32_16x16x32_bf16(a, b, c, 0, 0, 0);
}
__device__ __forceinline__ void stage16(const unsigned short* g, unsigned short* l) {
  __builtin_amdgcn_global_load_lds((const __attribute__((address_space(1))) void*)g,
                                   (__attribute__((address_space(3))) void*)l, 16, 0, 0);
}
__device__ __forceinline__ unsigned int cvtpk(float a, float b) {
  unsigned int r;
  asm("v_cvt_pk_bf16_f32 %0, %1, %2" : "=v"(r) : "v"(a), "v"(b));
  return r;
}
// interleaved V^T column position within each 32-chunk
__device__ __forceinline__ int Fj(int j) {
  return (j & ~31) | ((j & 15) << 1) | ((j >> 4) & 1);
}

// ---------------- weight transpose + bf16 convert ----------------
__global__ void k_prep(const float* __restrict__ Wq, const float* __restrict__ Wkv,
                       const float* __restrict__ Wctx, const float* __restrict__ Wout,
                       unsigned short* __restrict__ WqT, unsigned short* __restrict__ WkvT,
                       unsigned short* __restrict__ WctxT, unsigned short* __restrict__ WoutT) {
  int idx = blockIdx.x * 256 + threadIdx.x;
  if (idx < 262144) {
    int n = idx >> 9, k = idx & 511;
    WqT[idx] = f2bf(Wq[k * 512 + n]);
  } else if ((idx -= 262144) < 65536) {
    int n = idx >> 9, k = idx & 511;
    WkvT[idx] = f2bf(Wkv[k * 128 + n]);
  } else if ((idx -= 65536) < 98304) {
    int n = idx / 768, k = idx - n * 768;
    WctxT[idx] = f2bf(Wctx[k * 128 + n]);
  } else {
    idx -= 98304;
    int n = idx >> 9, k = idx & 511;
    WoutT[idx] = f2bf(Wout[k * 512 + n]);
  }
}

// ---------------- LN over C of x (B,C,N) -> xn bf16 (B*N, C) ----------------
__global__ void k_ln1(const float* __restrict__ x, const float* __restrict__ g,
                      unsigned short* __restrict__ xn) {
  int b = blockIdx.y;
  int i0 = blockIdx.x * 32;
  int t = threadIdx.x;
  int ii = t & 31, ci = t >> 5;
  const float* xb = x + (size_t)b * CDIM * NSEQ;
  float s = 0.f, s2 = 0.f;
  for (int c = ci; c < CDIM; c += 8) {
    float v = xb[(size_t)c * NSEQ + i0 + ii];
    s += v; s2 += v * v;
  }
  __shared__ float ls[8][32], ls2[8][32];
  __shared__ float lmu[32], lrs[32];
  ls[ci][ii] = s; ls2[ci][ii] = s2;
  __syncthreads();
  if (t < 32) {
    float a = 0.f, a2 = 0.f;
    for (int q = 0; q < 8; q++) { a += ls[q][t]; a2 += ls2[q][t]; }
    float mu = a * (1.0f / 512.0f);
    float var = a2 * (1.0f / 512.0f) - mu * mu;
    lmu[t] = mu; lrs[t] = rsqrtf(var + 1e-5f);
  }
  __syncthreads();
  float mu = lmu[ii], rs = lrs[ii];
  unsigned short* xrow = xn + (size_t)(b * NSEQ + i0 + ii) * CDIM;
  for (int c = ci; c < CDIM; c += 8) {
    float v = xb[(size_t)c * NSEQ + i0 + ii];
    xrow[c] = f2bf((v - mu) * rs * g[c]);
  }
}

// ---------------- context LN + projection; null row + zero pads ----------
__global__ void k_ctx(const float* __restrict__ ctx, const float* __restrict__ g,
                      const float* __restrict__ be, const unsigned short* __restrict__ WctxT,
                      const float* __restrict__ bctx, const float* __restrict__ null_kv,
                      unsigned short* __restrict__ kb, unsigned short* __restrict__ vt) {
  int b = blockIdx.y, j = blockIdx.x;
  int t = threadIdx.x;
  if (j == 77) {
    if (t < 64) kb[((size_t)b * LPAD + 77) * 64 + t] = f2bf(null_kv[t]);
    else vt[((size_t)b * 64 + (t - 64)) * LPAD + Fj(77)] = f2bf(null_kv[64 + (t - 64)]);
    return;
  }
  if (j > 77) {
    int jj = LKV + (j - 78);
    if (t < 64) kb[((size_t)b * LPAD + jj) * 64 + t] = 0;
    else vt[((size_t)b * 64 + (t - 64)) * LPAD + Fj(jj)] = 0;
    return;
  }
  __shared__ float row[768];
  __shared__ float red[4];
  const float* src = ctx + (size_t)(b * 77 + j) * 768;
  float s = 0.f, s2 = 0.f;
  for (int k = t; k < 768; k += 128) {
    float v = src[k];
    row[k] = v; s += v; s2 += v * v;
  }
  for (int o = 32; o; o >>= 1) { s += __shfl_xor(s, o); s2 += __shfl_xor(s2, o); }
  if ((t & 63) == 0) { red[(t >> 6) * 2] = s; red[(t >> 6) * 2 + 1] = s2; }
  __syncthreads();
  float S = red[0] + red[2], S2 = red[1] + red[3];
  float mu = S * (1.0f / 768.0f);
  float rs = rsqrtf(S2 * (1.0f / 768.0f) - mu * mu + 1e-5f);
  __syncthreads();
  for (int k = t; k < 768; k += 128) row[k] = (row[k] - mu) * rs * g[k] + be[k];
  __syncthreads();
  const uint4* w4 = reinterpret_cast<const uint4*>(WctxT + (size_t)t * 768);
  float acc = 0.f;
  for (int k8 = 0; k8 < 96; k8++) {
    union { uint4 u; unsigned short s[8]; } wv;
    wv.u = w4[k8];
#pragma unroll
    for (int e = 0; e < 8; e++) acc += row[k8 * 8 + e] * bf2f(wv.s[e]);
  }
  acc += bctx[t];
  if (t < 64) kb[((size_t)b * LPAD + j) * 64 + t] = f2bf(acc);
  else vt[((size_t)b * 64 + (t - 64)) * LPAD + Fj(j)] = f2bf(acc);
}

// ---------------- MFMA GEMM ----------------
template <int MODE>
__global__ __launch_bounds__(256, 1) void k_gemm(
    const unsigned short* __restrict__ A, const unsigned short* __restrict__ BT0,
    const unsigned short* __restrict__ BT1, unsigned short* __restrict__ out_q,
    unsigned short* __restrict__ out_k, unsigned short* __restrict__ out_vt,
    float* __restrict__ out_proj) {
  int m0 = blockIdx.x * 128, n0 = blockIdx.y * 128;
  int t = threadIdx.x;
  int lane = t & 63, w = t >> 6;
  int wm = w >> 1, wn = w & 1;
  int G = lane >> 4, li = lane & 15;
  __shared__ unsigned short Al[128][72];
  __shared__ unsigned short Bl[128][72];
  const unsigned short* BT = (MODE == 0 && n0 >= 512) ? BT1 : BT0;
  int bn0 = (MODE == 0 && n0 >= 512) ? n0 - 512 : n0;
  f32x4 zero = {0.f, 0.f, 0.f, 0.f};
  f32x4 acc[4][4];
#pragma unroll
  for (int a = 0; a < 4; a++)
#pragma unroll
    for (int c = 0; c < 4; c++) acc[a][c] = zero;
  int sr = t >> 1, sc = (t & 1) * 32;
  for (int k0 = 0; k0 < 512; k0 += 64) {
    const uint4* sA = reinterpret_cast<const uint4*>(A + (size_t)(m0 + sr) * 512 + k0 + sc);
    const uint4* sB = reinterpret_cast<const uint4*>(BT + (size_t)(bn0 + sr) * 512 + k0 + sc);
    uint4 a0 = sA[0], a1 = sA[1], a2 = sA[2], a3 = sA[3];
    uint4 b0 = sB[0], b1 = sB[1], b2 = sB[2], b3 = sB[3];
    uint4* dA = reinterpret_cast<uint4*>(&Al[sr][sc]);
    uint4* dB = reinterpret_cast<uint4*>(&Bl[sr][sc]);
    dA[0] = a0; dA[1] = a1; dA[2] = a2; dA[3] = a3;
    dB[0] = b0; dB[1] = b1; dB[2] = b2; dB[3] = b3;
    __syncthreads();
#pragma unroll
    for (int ks = 0; ks < 2; ks++) {
      bf16x8 af[4], bfr[4];
#pragma unroll
      for (int f = 0; f < 4; f++) {
        af[f] = *reinterpret_cast<const bf16x8*>(&Al[wm * 64 + f * 16 + li][ks * 32 + G * 8]);
        bfr[f] = *reinterpret_cast<const bf16x8*>(&Bl[wn * 64 + f * 16 + li][ks * 32 + G * 8]);
      }
#pragma unroll
      for (int fm = 0; fm < 4; fm++)
#pragma unroll
        for (int fn = 0; fn < 4; fn++)
          acc[fm][fn] = MFMA(af[fm], bfr[fn], acc[fm][fn]);
    }
    __syncthreads();
  }
#pragma unroll
  for (int fm = 0; fm < 4; fm++)
#pragma unroll
    for (int fn = 0; fn < 4; fn++)
#pragma unroll
      for (int r = 0; r < 4; r++) {
        int row = m0 + wm * 64 + fm * 16 + G * 4 + r;
        int col = n0 + wn * 64 + fn * 16 + li;
        float v = acc[fm][fn][r];
        if (MODE == 0) {
          int b = row / NSEQ, i = row - b * NSEQ;
          // q pre-scaled by 1/sqrt(dh) * log2(e): softmax runs in exp2 domain
          if (col < 512) out_q[(size_t)row * 512 + col] = f2bf(v * 0.18033688011112042f);
          else if (col < 576) out_k[((size_t)b * LPAD + 78 + i) * 64 + (col - 512)] = f2bf(v);
          else out_vt[((size_t)b * 64 + (col - 576)) * LPAD + Fj(78 + i)] = f2bf(v);
        } else {
          out_proj[(size_t)row * 512 + col] = v;
        }
      }
}

// ---------------- flash attention: 2-way KV split, 8 waves = 8 heads --------
// Block = 512 threads; wave w owns head w; one K/V staging serves all 8 heads.
// __launch_bounds__(512,2): VGPR cap 256 — this wave needs ~96 regs; any
// bound implying >4 waves/SIMD caps VGPR at 64 and spills ~650MB (R10 lesson).
// no-max exp2 softmax -> split partials combine by pure addition.
// K tile [64j][64d]; V^T tile [64d][64 interleaved-j] (Fj layout) staged via
// global_load_lds (ONE stage16 per thread per tile), source-side XOR swizzle.
// Double-buffer parity is LOCAL (u&1).
__global__ __launch_bounds__(512, 2) void k_attn(
    const unsigned short* __restrict__ q, const unsigned short* __restrict__ kbuf,
    const unsigned short* __restrict__ vt, unsigned short* __restrict__ pO0,
    unsigned short* __restrict__ pO1, float* __restrict__ lp) {
  int bx = blockIdx.x;
  int it = bx >> 1, sp = bx & 1;
  int b = blockIdx.z;
  int i0 = it * 32;
  int t = threadIdx.x;
  int w = t >> 6, lane = t & 63;
  int G = lane >> 4, li = lane & 15, li7 = lane & 7;
  int h = w;  // wave = head

  __shared__ __align__(16) unsigned short Kl[2][4096];
  __shared__ __align__(16) unsigned short Vl[2][4096];

  int r1 = t >> 3;                       // 0..63 (full tile row)
  int c1 = ((t & 7) ^ (r1 & 7)) * 8;     // swizzled 16B-granule column

  const unsigned short* kbase = kbuf + (size_t)b * LPAD * 64;
  const unsigned short* vbase = vt + (size_t)b * 64 * LPAD;

  bf16x8 qf[2][2];
#pragma unroll
  for (int fi = 0; fi < 2; fi++)
#pragma unroll
    for (int ks = 0; ks < 2; ks++)
      qf[fi][ks] = *reinterpret_cast<const bf16x8*>(
          q + (size_t)(b * NSEQ + i0 + fi * 16 + li) * CDIM + h * 64 + ks * 32 + G * 8);

  int jt0 = sp * 19;

  // stage first tile of this split into buffer [0]
  {
    int j0 = jt0 * 64;
    stage16(kbase + (size_t)(j0 + r1) * 64 + c1, &Kl[0][w * 512]);
    stage16(vbase + (size_t)r1 * LPAD + j0 + c1, &Vl[0][w * 512]);
  }

  f32x4 zero = {0.f, 0.f, 0.f, 0.f};
  f32x4 OT[4][2];  // [fd][fi]; row d = fd*16+G*4+r, col i = fi*16+li
#pragma unroll
  for (int fd = 0; fd < 4; fd++)
#pragma unroll
    for (int fi = 0; fi < 2; fi++) OT[fd][fi] = zero;
  float l_[2] = {0.f, 0.f};

  __syncthreads();

  for (int u = 0; u < 19; u++) {
    int jt = jt0 + u;
    int cur = u & 1, nxt = cur ^ 1;  // LOCAL parity
    int j0 = jt * 64;
    if (u + 1 < 19) {
      int j1 = j0 + 64;
      stage16(kbase + (size_t)(j1 + r1) * 64 + c1, &Kl[nxt][w * 512]);
      stage16(vbase + (size_t)r1 * LPAD + j1 + c1, &Vl[nxt][w * 512]);
    }
    const char* Kc = (const char*)Kl[cur];
    const char* Vc = (const char*)Vl[cur];

    f32x4 S[4][2];
#pragma unroll
    for (int fj = 0; fj < 4; fj++) { S[fj][0] = zero; S[fj][1] = zero; }
#pragma unroll
    for (int ks = 0; ks < 2; ks++) {
      bf16x8 kf[4];
#pragma unroll
      for (int fj = 0; fj < 4; fj++)
        kf[fj] = *reinterpret_cast<const bf16x8*>(
            Kc + ((((fj * 16 + li) * 8) + ((ks * 4 + G) ^ li7)) << 4));
#pragma unroll
      for (int fj = 0; fj < 4; fj++)
#pragma unroll
        for (int fi = 0; fi < 2; fi++)
          S[fj][fi] = MFMA(kf[fj], qf[fi][ks], S[fj][fi]);
    }
    if (j0 + 64 > LKV) {
#pragma unroll
      for (int fj = 0; fj < 4; fj++)
#pragma unroll
        for (int r = 0; r < 4; r++) {
          int jg = j0 + fj * 16 + G * 4 + r;
          if (jg >= LKV) { S[fj][0][r] = -1e30f; S[fj][1][r] = -1e30f; }
        }
    }
    // no-max softmax: e = exp2(S); pack pf in interleaved-j bijection:
    // B k-slot (G,E) <-> j = ks*32 + (E&1)*16 + G*4 + (E>>1)
    bf16x8 pf[2][2];
#pragma unroll
    for (int fi = 0; fi < 2; fi++) {
      float e[4][4];
#pragma unroll
      for (int fj = 0; fj < 4; fj++)
#pragma unroll
        for (int r = 0; r < 4; r++) e[fj][r] = __builtin_exp2f(S[fj][fi][r]);
      float s0 = (e[0][0] + e[0][1]) + (e[0][2] + e[0][3]);
      float s1 = (e[1][0] + e[1][1]) + (e[1][2] + e[1][3]);
      float s2 = (e[2][0] + e[2][1]) + (e[2][2] + e[2][3]);
      float s3 = (e[3][0] + e[3][1]) + (e[3][2] + e[3][3]);
      l_[fi] += (s0 + s1) + (s2 + s3);
#pragma unroll
      for (int ks = 0; ks < 2; ks++) {
        union { unsigned int w4[4]; bf16x8 v; } u2;
#pragma unroll
        for (int m = 0; m < 4; m++) u2.w4[m] = cvtpk(e[2 * ks][m], e[2 * ks + 1][m]);
        pf[fi][ks] = u2.v;
      }
    }
    // PV from LDS V^T (interleaved layout): one b128 per (ks, fd)
#pragma unroll
    for (int ks = 0; ks < 2; ks++) {
#pragma unroll
      for (int fd = 0; fd < 4; fd++) {
        bf16x8 uv = *reinterpret_cast<const bf16x8*>(
            Vc + (((fd * 16 + li) * 8 + ((ks * 4 + G) ^ li7)) << 4));
#pragma unroll
        for (int fi = 0; fi < 2; fi++) OT[fd][fi] = MFMA(uv, pf[fi][ks], OT[fd][fi]);
      }
    }
    __syncthreads();
  }

  // write unnormalized partials + l partials
  unsigned short* pO = sp ? pO1 : pO0;
#pragma unroll
  for (int fi = 0; fi < 2; fi++) {
    l_[fi] += __shfl_xor(l_[fi], 16);
    l_[fi] += __shfl_xor(l_[fi], 32);
    int row = b * NSEQ + i0 + fi * 16 + li;
    if (G == 0) lp[sp * LPROWS + row * 8 + h] = l_[fi];
#pragma unroll
    for (int fd = 0; fd < 4; fd++) {
      union { unsigned int w2[2]; uint2 u2; } pk;
      pk.w2[0] = cvtpk(OT[fd][fi][0], OT[fd][fi][1]);
      pk.w2[1] = cvtpk(OT[fd][fi][2], OT[fd][fi][3]);
      *reinterpret_cast<uint2*>(pO + (size_t)row * CDIM + h * 64 + fd * 16 + G * 4) = pk.u2;
    }
  }
}

// ---------------- merge the two KV-split partials ----------------
// out (in place over pO0) = (O0 + O1) / (l0 + l1), bf16
__global__ void k_merge(unsigned short* __restrict__ pO0,
                        const unsigned short* __restrict__ pO1,
                        const float* __restrict__ lp) {
  int c = blockIdx.x * 256 + threadIdx.x;  // 16B chunk index (8 bf16)
  size_t base = (size_t)c * 8;
  int row = (int)(base >> 9);
  int h = (int)((base >> 6) & 7);
  float l = lp[row * 8 + h] + lp[LPROWS + row * 8 + h];
  float inv = 1.0f / l;
  union { uint4 u; unsigned short s[8]; } a, bq, o;
  a.u = *reinterpret_cast<const uint4*>(pO0 + base);
  bq.u = *reinterpret_cast<const uint4*>(pO1 + base);
  unsigned int* ow = reinterpret_cast<unsigned int*>(&o.u);
#pragma unroll
  for (int m = 0; m < 4; m++) {
    float v0 = (bf2f(a.s[2 * m]) + bf2f(bq.s[2 * m])) * inv;
    float v1 = (bf2f(a.s[2 * m + 1]) + bf2f(bq.s[2 * m + 1])) * inv;
    ow[m] = cvtpk(v0, v1);
  }
  *reinterpret_cast<uint4*>(pO0 + base) = o.u;
}

// ---------------- per-row LN stats of proj (coalesced) ----------------
__global__ void k_stats(const float* __restrict__ proj, float* __restrict__ musig) {
  int w = threadIdx.x >> 6, lane = threadIdx.x & 63;
  int row = blockIdx.x * 4 + w;
  const float* pr = proj + (size_t)row * CDIM;
  const float4* p4 = reinterpret_cast<const float4*>(pr + lane * 8);
  float4 a = p4[0], bq = p4[1];
  float s = a.x + a.y + a.z + a.w + bq.x + bq.y + bq.z + bq.w;
  float s2 = a.x * a.x + a.y * a.y + a.z * a.z + a.w * a.w +
             bq.x * bq.x + bq.y * bq.y + bq.z * bq.z + bq.w * bq.w;
  for (int o = 32; o; o >>= 1) { s += __shfl_xor(s, o); s2 += __shfl_xor(s2, o); }
  if (lane == 0) {
    float mu = s * (1.0f / 512.0f);
    float var = s2 * (1.0f / 512.0f) - mu * mu;
    musig[row] = mu;
    musig[4 * NSEQ + row] = rsqrtf(var + 1e-5f);
  }
}

// ---------------- final LN + residual, LDS-transposed, fully coalesced ------
__global__ void k_final2(const float* __restrict__ proj, const float* __restrict__ musig,
                         const float* __restrict__ g, const float* __restrict__ x,
                         float* __restrict__ y) {
  int i0 = blockIdx.x * 32, c0 = blockIdx.y * 64, b = blockIdx.z;
  int t = threadIdx.x;
  __shared__ float lds[32][65];
  {
    int il = t >> 3, cB = (t & 7) * 8;
    const float4* src = reinterpret_cast<const float4*>(
        proj + (size_t)(b * NSEQ + i0 + il) * CDIM + c0 + cB);
    float4 v0 = src[0], v1 = src[1];
    *reinterpret_cast<float4*>(&lds[il][cB]) = v0;
    *reinterpret_cast<float4*>(&lds[il][cB + 4]) = v1;
  }
  __syncthreads();
  int ii = t & 31, cg = t >> 5;
  float mu = musig[b * NSEQ + i0 + ii];
  float rs = musig[4 * NSEQ + b * NSEQ + i0 + ii];
  const float* xb = x + (size_t)b * CDIM * NSEQ;
  float* yb = y + (size_t)b * CDIM * NSEQ;
#pragma unroll
  for (int cc = 0; cc < 8; cc++) {
    int cl = cg * 8 + cc;
    int c = c0 + cl;
    float v = lds[ii][cl];
    yb[(size_t)c * NSEQ + i0 + ii] = xb[(size_t)c * NSEQ + i0 + ii] + (v - mu) * rs * g[c];
  }
}

extern "C" void kernel_launch(void* const* d_in, const int* in_sizes, int n_in,
                              void* d_out, int out_size, void* d_ws, size_t ws_size,
                              hipStream_t stream) {
  const float* x       = (const float*)d_in[0];
  const float* context = (const float*)d_in[1];
  const float* ngamma  = (const float*)d_in[2];
  const float* null_kv = (const float*)d_in[3];
  const float* Wq      = (const float*)d_in[4];
  const float* Wkv     = (const float*)d_in[5];
  const float* clng    = (const float*)d_in[6];
  const float* clnb    = (const float*)d_in[7];
  const float* Wctx    = (const float*)d_in[8];
  const float* bctx    = (const float*)d_in[9];
  const float* Wout    = (const float*)d_in[10];
  const float* olng    = (const float*)d_in[11];
  float* y = (float*)d_out;
  char* ws = (char*)d_ws;

  unsigned short* xn    = (unsigned short*)(ws);              // 9437184 B (also pO1 during attn)
  unsigned short* qb    = (unsigned short*)(ws + 9437184);    // 9437184 B
  float* proj           = (float*)(ws);                       // aliases xn+qb (dead by then)
  unsigned short* aoutb = (unsigned short*)(ws + 18874368);   // 9437184 B (pO0 -> merged)
  float* musig          = (float*)(ws + 18874368);            // aliases aoutb (dead after gemm1)
  unsigned short* kb    = (unsigned short*)(ws + 28311552);   // 1245184 B
  unsigned short* vtb   = (unsigned short*)(ws + 29556736);   // 1245184 B
  unsigned short* WqT   = (unsigned short*)(ws + 30801920);   // 524288 B
  unsigned short* WkvT  = (unsigned short*)(ws + 31326208);   // 131072 B
  unsigned short* WctxT = (unsigned short*)(ws + 31457280);   // 196608 B
  unsigned short* WoutT = (unsigned short*)(ws + 31653888);   // 524288 B
  // l-partials (589824 B) overlay WqT+WkvT (655360 B) — dead after k_gemm<0>
  float* lpart          = (float*)(ws + 30801920);

  k_prep<<<dim3(2688), dim3(256), 0, stream>>>(Wq, Wkv, Wctx, Wout, WqT, WkvT, WctxT, WoutT);
  k_ln1<<<dim3(72, 4), dim3(256), 0, stream>>>(x, ngamma, xn);
  k_ctx<<<dim3(128, 4), dim3(128), 0, stream>>>(context, clng, clnb, WctxT, bctx, null_kv, kb, vtb);
  k_gemm<0><<<dim3(72, 5), dim3(256), 0, stream>>>(xn, WqT, WkvT, qb, kb, vtb, nullptr);
  k_attn<<<dim3(144, 1, 4), dim3(512), 0, stream>>>(qb, kb, vtb, aoutb, xn, lpart);
  k_merge<<<dim3(2304), dim3(256), 0, stream>>>(aoutb, xn, lpart);
  k_gemm<1><<<dim3(72, 4), dim3(256), 0, stream>>>(aoutb, WoutT, nullptr, nullptr, nullptr, nullptr, proj);
  k_stats<<<dim3(2304), dim3(256), 0, stream>>>(proj, musig);
  k_final2<<<dim3(72, 8, 4), dim3(256), 0, stream>>>(proj, musig, olng, x, y);
}

// Round 12
// 196.850 us; speedup vs baseline: 2.8167x; 1.0498x over previous
//
#include <hip/hip_runtime.h>

typedef __attribute__((ext_vector_type(8))) short bf16x8;
typedef __attribute__((ext_vector_type(4))) float f32x4;

#define LPAD 2432
#define LKV  2382
#define NSEQ 2304
#define CDIM 512
#define LPSZ (4 * NSEQ * 8)  // l-partial entries per split (rows*heads)

__device__ __forceinline__ unsigned short f2bf(float f) {
  unsigned int u = __builtin_bit_cast(unsigned int, f);
  u += 0x7fffu + ((u >> 16) & 1u);
  return (unsigned short)(u >> 16);
}
__device__ __forceinline__ float bf2f(unsigned short s) {
  unsigned int u = ((unsigned int)s) << 16;
  return __builtin_bit_cast(float, u);
}
__device__ __forceinline__ f32x4 MFMA(bf16x8 a, bf16x8 b, f32x4 c) {
  return __builtin_amdgcn_mfma_f32_16x16x32_bf16(a, b, c, 0, 0, 0);
}
__device__ __forceinline__ void stage16(const unsigned short* g, unsigned short* l) {
  __builtin_amdgcn_global_load_lds((const __attribute__((address_space(1))) void*)g,
                                   (__attribute__((address_space(3))) void*)l, 16, 0, 0);
}
__device__ __forceinline__ unsigned int cvtpk(float a, float b) {
  unsigned int r;
  asm("v_cvt_pk_bf16_f32 %0, %1, %2" : "=v"(r) : "v"(a), "v"(b));
  return r;
}
// interleaved V^T column position within each 32-chunk
__device__ __forceinline__ int Fj(int j) {
  return (j & ~31) | ((j & 15) << 1) | ((j >> 4) & 1);
}

// ---------------- weight transpose + bf16 convert ----------------
__global__ void k_prep(const float* __restrict__ Wq, const float* __restrict__ Wkv,
                       const float* __restrict__ Wctx, const float* __restrict__ Wout,
                       unsigned short* __restrict__ WqT, unsigned short* __restrict__ WkvT,
                       unsigned short* __restrict__ WctxT, unsigned short* __restrict__ WoutT) {
  int idx = blockIdx.x * 256 + threadIdx.x;
  if (idx < 262144) {
    int n = idx >> 9, k = idx & 511;
    WqT[idx] = f2bf(Wq[k * 512 + n]);
  } else if ((idx -= 262144) < 65536) {
    int n = idx >> 9, k = idx & 511;
    WkvT[idx] = f2bf(Wkv[k * 128 + n]);
  } else if ((idx -= 65536) < 98304) {
    int n = idx / 768, k = idx - n * 768;
    WctxT[idx] = f2bf(Wctx[k * 128 + n]);
  } else {
    idx -= 98304;
    int n = idx >> 9, k = idx & 511;
    WoutT[idx] = f2bf(Wout[k * 512 + n]);
  }
}

// ---------------- LN over C of x (B,C,N) -> xn bf16 (B*N, C) ----------------
__global__ void k_ln1(const float* __restrict__ x, const float* __restrict__ g,
                      unsigned short* __restrict__ xn) {
  int b = blockIdx.y;
  int i0 = blockIdx.x * 32;
  int t = threadIdx.x;
  int ii = t & 31, ci = t >> 5;
  const float* xb = x + (size_t)b * CDIM * NSEQ;
  float s = 0.f, s2 = 0.f;
  for (int c = ci; c < CDIM; c += 8) {
    float v = xb[(size_t)c * NSEQ + i0 + ii];
    s += v; s2 += v * v;
  }
  __shared__ float ls[8][32], ls2[8][32];
  __shared__ float lmu[32], lrs[32];
  ls[ci][ii] = s; ls2[ci][ii] = s2;
  __syncthreads();
  if (t < 32) {
    float a = 0.f, a2 = 0.f;
    for (int q = 0; q < 8; q++) { a += ls[q][t]; a2 += ls2[q][t]; }
    float mu = a * (1.0f / 512.0f);
    float var = a2 * (1.0f / 512.0f) - mu * mu;
    lmu[t] = mu; lrs[t] = rsqrtf(var + 1e-5f);
  }
  __syncthreads();
  float mu = lmu[ii], rs = lrs[ii];
  unsigned short* xrow = xn + (size_t)(b * NSEQ + i0 + ii) * CDIM;
  for (int c = ci; c < CDIM; c += 8) {
    float v = xb[(size_t)c * NSEQ + i0 + ii];
    xrow[c] = f2bf((v - mu) * rs * g[c]);
  }
}

// ---------------- context LN + projection; null row + zero pads ----------
__global__ void k_ctx(const float* __restrict__ ctx, const float* __restrict__ g,
                      const float* __restrict__ be, const unsigned short* __restrict__ WctxT,
                      const float* __restrict__ bctx, const float* __restrict__ null_kv,
                      unsigned short* __restrict__ kb, unsigned short* __restrict__ vt) {
  int b = blockIdx.y, j = blockIdx.x;
  int t = threadIdx.x;
  if (j == 77) {
    if (t < 64) kb[((size_t)b * LPAD + 77) * 64 + t] = f2bf(null_kv[t]);
    else vt[((size_t)b * 64 + (t - 64)) * LPAD + Fj(77)] = f2bf(null_kv[64 + (t - 64)]);
    return;
  }
  if (j > 77) {
    int jj = LKV + (j - 78);
    if (t < 64) kb[((size_t)b * LPAD + jj) * 64 + t] = 0;
    else vt[((size_t)b * 64 + (t - 64)) * LPAD + Fj(jj)] = 0;
    return;
  }
  __shared__ float row[768];
  __shared__ float red[4];
  const float* src = ctx + (size_t)(b * 77 + j) * 768;
  float s = 0.f, s2 = 0.f;
  for (int k = t; k < 768; k += 128) {
    float v = src[k];
    row[k] = v; s += v; s2 += v * v;
  }
  for (int o = 32; o; o >>= 1) { s += __shfl_xor(s, o); s2 += __shfl_xor(s2, o); }
  if ((t & 63) == 0) { red[(t >> 6) * 2] = s; red[(t >> 6) * 2 + 1] = s2; }
  __syncthreads();
  float S = red[0] + red[2], S2 = red[1] + red[3];
  float mu = S * (1.0f / 768.0f);
  float rs = rsqrtf(S2 * (1.0f / 768.0f) - mu * mu + 1e-5f);
  __syncthreads();
  for (int k = t; k < 768; k += 128) row[k] = (row[k] - mu) * rs * g[k] + be[k];
  __syncthreads();
  const uint4* w4 = reinterpret_cast<const uint4*>(WctxT + (size_t)t * 768);
  float acc = 0.f;
  for (int k8 = 0; k8 < 96; k8++) {
    union { uint4 u; unsigned short s[8]; } wv;
    wv.u = w4[k8];
#pragma unroll
    for (int e = 0; e < 8; e++) acc += row[k8 * 8 + e] * bf2f(wv.s[e]);
  }
  acc += bctx[t];
  if (t < 64) kb[((size_t)b * LPAD + j) * 64 + t] = f2bf(acc);
  else vt[((size_t)b * 64 + (t - 64)) * LPAD + Fj(j)] = f2bf(acc);
}

// ---------------- MFMA GEMM ----------------
template <int MODE>
__global__ __launch_bounds__(256, 1) void k_gemm(
    const unsigned short* __restrict__ A, const unsigned short* __restrict__ BT0,
    const unsigned short* __restrict__ BT1, unsigned short* __restrict__ out_q,
    unsigned short* __restrict__ out_k, unsigned short* __restrict__ out_vt,
    float* __restrict__ out_proj) {
  int m0 = blockIdx.x * 128, n0 = blockIdx.y * 128;
  int t = threadIdx.x;
  int lane = t & 63, w = t >> 6;
  int wm = w >> 1, wn = w & 1;
  int G = lane >> 4, li = lane & 15;
  __shared__ unsigned short Al[128][72];
  __shared__ unsigned short Bl[128][72];
  const unsigned short* BT = (MODE == 0 && n0 >= 512) ? BT1 : BT0;
  int bn0 = (MODE == 0 && n0 >= 512) ? n0 - 512 : n0;
  f32x4 zero = {0.f, 0.f, 0.f, 0.f};
  f32x4 acc[4][4];
#pragma unroll
  for (int a = 0; a < 4; a++)
#pragma unroll
    for (int c = 0; c < 4; c++) acc[a][c] = zero;
  int sr = t >> 1, sc = (t & 1) * 32;
  for (int k0 = 0; k0 < 512; k0 += 64) {
    const uint4* sA = reinterpret_cast<const uint4*>(A + (size_t)(m0 + sr) * 512 + k0 + sc);
    const uint4* sB = reinterpret_cast<const uint4*>(BT + (size_t)(bn0 + sr) * 512 + k0 + sc);
    uint4 a0 = sA[0], a1 = sA[1], a2 = sA[2], a3 = sA[3];
    uint4 b0 = sB[0], b1 = sB[1], b2 = sB[2], b3 = sB[3];
    uint4* dA = reinterpret_cast<uint4*>(&Al[sr][sc]);
    uint4* dB = reinterpret_cast<uint4*>(&Bl[sr][sc]);
    dA[0] = a0; dA[1] = a1; dA[2] = a2; dA[3] = a3;
    dB[0] = b0; dB[1] = b1; dB[2] = b2; dB[3] = b3;
    __syncthreads();
#pragma unroll
    for (int ks = 0; ks < 2; ks++) {
      bf16x8 af[4], bfr[4];
#pragma unroll
      for (int f = 0; f < 4; f++) {
        af[f] = *reinterpret_cast<const bf16x8*>(&Al[wm * 64 + f * 16 + li][ks * 32 + G * 8]);
        bfr[f] = *reinterpret_cast<const bf16x8*>(&Bl[wn * 64 + f * 16 + li][ks * 32 + G * 8]);
      }
#pragma unroll
      for (int fm = 0; fm < 4; fm++)
#pragma unroll
        for (int fn = 0; fn < 4; fn++)
          acc[fm][fn] = MFMA(af[fm], bfr[fn], acc[fm][fn]);
    }
    __syncthreads();
  }
#pragma unroll
  for (int fm = 0; fm < 4; fm++)
#pragma unroll
    for (int fn = 0; fn < 4; fn++)
#pragma unroll
      for (int r = 0; r < 4; r++) {
        int row = m0 + wm * 64 + fm * 16 + G * 4 + r;
        int col = n0 + wn * 64 + fn * 16 + li;
        float v = acc[fm][fn][r];
        if (MODE == 0) {
          int b = row / NSEQ, i = row - b * NSEQ;
          // q pre-scaled by 1/sqrt(dh) * log2(e): softmax runs in exp2 domain
          if (col < 512) out_q[(size_t)row * 512 + col] = f2bf(v * 0.18033688011112042f);
          else if (col < 576) out_k[((size_t)b * LPAD + 78 + i) * 64 + (col - 512)] = f2bf(v);
          else out_vt[((size_t)b * 64 + (col - 576)) * LPAD + Fj(78 + i)] = f2bf(v);
        } else {
          out_proj[(size_t)row * 512 + col] = v;
        }
      }
}

// ---------------- flash attention: 4-way KV split, 4 waves = 4 heads --------
// Block = 256 threads (4 waves, heads hh*4+w); grid 288x2x4 = 2304 blocks
// (9 supplied/CU; LDS 32KB -> 5 resident/CU). no-max exp2 softmax -> split
// partials combine by pure addition; partials 2,3 live in d_out (rewritten by
// k_final2). l-partials stored bf16 (0.2% rel err, negligible).
// K tile [64j][64d]; V^T tile [64d][64 interleaved-j] staged via
// global_load_lds with source-side XOR swizzle; LOCAL double-buffer parity.
__global__ __launch_bounds__(256, 2) void k_attn(
    const unsigned short* __restrict__ q, const unsigned short* __restrict__ kbuf,
    const unsigned short* __restrict__ vt, unsigned short* __restrict__ pO0,
    unsigned short* __restrict__ pO1, unsigned short* __restrict__ pO2,
    unsigned short* __restrict__ pO3, unsigned short* __restrict__ lp) {
  int bx = blockIdx.x;
  int it = bx >> 2, sp = bx & 3;
  int hh = blockIdx.y, b = blockIdx.z;
  int i0 = it * 32;
  int t = threadIdx.x;
  int w = t >> 6, lane = t & 63;
  int G = lane >> 4, li = lane & 15, li7 = lane & 7;
  int h = hh * 4 + w;

  __shared__ __align__(16) unsigned short Kl[2][4096];
  __shared__ __align__(16) unsigned short Vl[2][4096];

  int r1 = t >> 3;                       // 0..31
  int c1 = ((t & 7) ^ (r1 & 7)) * 8;     // swizzled 16B-granule column

  const unsigned short* kbase = kbuf + (size_t)b * LPAD * 64;
  const unsigned short* vbase = vt + (size_t)b * 64 * LPAD;

  bf16x8 qf[2][2];
#pragma unroll
  for (int fi = 0; fi < 2; fi++)
#pragma unroll
    for (int ks = 0; ks < 2; ks++)
      qf[fi][ks] = *reinterpret_cast<const bf16x8*>(
          q + (size_t)(b * NSEQ + i0 + fi * 16 + li) * CDIM + h * 64 + ks * 32 + G * 8);

  int jt0 = (sp * 38) >> 2;              // 0, 9, 19, 28
  int nt = (((sp + 1) * 38) >> 2) - jt0; // 9, 10, 9, 10

  // stage first tile of this split into buffer [0]
  {
    int j0 = jt0 * 64;
    stage16(kbase + (size_t)(j0 + r1) * 64 + c1, &Kl[0][w * 512]);
    stage16(kbase + (size_t)(j0 + r1 + 32) * 64 + c1, &Kl[0][2048 + w * 512]);
    stage16(vbase + (size_t)r1 * LPAD + j0 + c1, &Vl[0][w * 512]);
    stage16(vbase + (size_t)(r1 + 32) * LPAD + j0 + c1, &Vl[0][2048 + w * 512]);
  }

  f32x4 zero = {0.f, 0.f, 0.f, 0.f};
  f32x4 OT[4][2];  // [fd][fi]; row d = fd*16+G*4+r, col i = fi*16+li
#pragma unroll
  for (int fd = 0; fd < 4; fd++)
#pragma unroll
    for (int fi = 0; fi < 2; fi++) OT[fd][fi] = zero;
  float l_[2] = {0.f, 0.f};

  __syncthreads();

  for (int u = 0; u < nt; u++) {
    int jt = jt0 + u;
    int cur = u & 1, nxt = cur ^ 1;  // LOCAL parity
    int j0 = jt * 64;
    if (u + 1 < nt) {
      int j1 = j0 + 64;
      stage16(kbase + (size_t)(j1 + r1) * 64 + c1, &Kl[nxt][w * 512]);
      stage16(kbase + (size_t)(j1 + r1 + 32) * 64 + c1, &Kl[nxt][2048 + w * 512]);
      stage16(vbase + (size_t)r1 * LPAD + j1 + c1, &Vl[nxt][w * 512]);
      stage16(vbase + (size_t)(r1 + 32) * LPAD + j1 + c1, &Vl[nxt][2048 + w * 512]);
    }
    const char* Kc = (const char*)Kl[cur];
    const char* Vc = (const char*)Vl[cur];

    f32x4 S[4][2];
#pragma unroll
    for (int fj = 0; fj < 4; fj++) { S[fj][0] = zero; S[fj][1] = zero; }
#pragma unroll
    for (int ks = 0; ks < 2; ks++) {
      bf16x8 kf[4];
#pragma unroll
      for (int fj = 0; fj < 4; fj++)
        kf[fj] = *reinterpret_cast<const bf16x8*>(
            Kc + ((((fj * 16 + li) * 8) + ((ks * 4 + G) ^ li7)) << 4));
#pragma unroll
      for (int fj = 0; fj < 4; fj++)
#pragma unroll
        for (int fi = 0; fi < 2; fi++)
          S[fj][fi] = MFMA(kf[fj], qf[fi][ks], S[fj][fi]);
    }
    if (j0 + 64 > LKV) {
#pragma unroll
      for (int fj = 0; fj < 4; fj++)
#pragma unroll
        for (int r = 0; r < 4; r++) {
          int jg = j0 + fj * 16 + G * 4 + r;
          if (jg >= LKV) { S[fj][0][r] = -1e30f; S[fj][1][r] = -1e30f; }
        }
    }
    // no-max softmax: e = exp2(S); pack pf in interleaved-j bijection:
    // B k-slot (G,E) <-> j = ks*32 + (E&1)*16 + G*4 + (E>>1)
    bf16x8 pf[2][2];
#pragma unroll
    for (int fi = 0; fi < 2; fi++) {
      float e[4][4];
#pragma unroll
      for (int fj = 0; fj < 4; fj++)
#pragma unroll
        for (int r = 0; r < 4; r++) e[fj][r] = __builtin_exp2f(S[fj][fi][r]);
      float s0 = (e[0][0] + e[0][1]) + (e[0][2] + e[0][3]);
      float s1 = (e[1][0] + e[1][1]) + (e[1][2] + e[1][3]);
      float s2 = (e[2][0] + e[2][1]) + (e[2][2] + e[2][3]);
      float s3 = (e[3][0] + e[3][1]) + (e[3][2] + e[3][3]);
      l_[fi] += (s0 + s1) + (s2 + s3);
#pragma unroll
      for (int ks = 0; ks < 2; ks++) {
        union { unsigned int w4[4]; bf16x8 v; } u2;
#pragma unroll
        for (int m = 0; m < 4; m++) u2.w4[m] = cvtpk(e[2 * ks][m], e[2 * ks + 1][m]);
        pf[fi][ks] = u2.v;
      }
    }
    // PV from LDS V^T (interleaved layout): one b128 per (ks, fd)
#pragma unroll
    for (int ks = 0; ks < 2; ks++) {
#pragma unroll
      for (int fd = 0; fd < 4; fd++) {
        bf16x8 uv = *reinterpret_cast<const bf16x8*>(
            Vc + (((fd * 16 + li) * 8 + ((ks * 4 + G) ^ li7)) << 4));
#pragma unroll
        for (int fi = 0; fi < 2; fi++) OT[fd][fi] = MFMA(uv, pf[fi][ks], OT[fd][fi]);
      }
    }
    __syncthreads();
  }

  // write unnormalized partials + bf16 l partials
  unsigned short* pO = (sp == 0) ? pO0 : (sp == 1) ? pO1 : (sp == 2) ? pO2 : pO3;
#pragma unroll
  for (int fi = 0; fi < 2; fi++) {
    l_[fi] += __shfl_xor(l_[fi], 16);
    l_[fi] += __shfl_xor(l_[fi], 32);
    int row = b * NSEQ + i0 + fi * 16 + li;
    if (G == 0) lp[sp * LPSZ + row * 8 + h] = f2bf(l_[fi]);
#pragma unroll
    for (int fd = 0; fd < 4; fd++) {
      union { unsigned int w2[2]; uint2 u2; } pk;
      pk.w2[0] = cvtpk(OT[fd][fi][0], OT[fd][fi][1]);
      pk.w2[1] = cvtpk(OT[fd][fi][2], OT[fd][fi][3]);
      *reinterpret_cast<uint2*>(pO + (size_t)row * CDIM + h * 64 + fd * 16 + G * 4) = pk.u2;
    }
  }
}

// ---------------- merge the four KV-split partials ----------------
// out (in place over pO0) = (O0+O1+O2+O3) / (l0+l1+l2+l3), bf16
__global__ void k_merge(unsigned short* __restrict__ pO0,
                        const unsigned short* __restrict__ pO1,
                        const unsigned short* __restrict__ pO2,
                        const unsigned short* __restrict__ pO3,
                        const unsigned short* __restrict__ lp) {
  int c = blockIdx.x * 256 + threadIdx.x;  // 16B chunk index (8 bf16)
  size_t base = (size_t)c * 8;
  int row = (int)(base >> 9);
  int h = (int)((base >> 6) & 7);
  int li = row * 8 + h;
  float l = bf2f(lp[li]) + bf2f(lp[LPSZ + li]) + bf2f(lp[2 * LPSZ + li]) + bf2f(lp[3 * LPSZ + li]);
  float inv = 1.0f / l;
  union { uint4 u; unsigned short s[8]; } a0, a1, a2, a3, o;
  a0.u = *reinterpret_cast<const uint4*>(pO0 + base);
  a1.u = *reinterpret_cast<const uint4*>(pO1 + base);
  a2.u = *reinterpret_cast<const uint4*>(pO2 + base);
  a3.u = *reinterpret_cast<const uint4*>(pO3 + base);
  unsigned int* ow = reinterpret_cast<unsigned int*>(&o.u);
#pragma unroll
  for (int m = 0; m < 4; m++) {
    float v0 = (bf2f(a0.s[2 * m]) + bf2f(a1.s[2 * m]) + bf2f(a2.s[2 * m]) + bf2f(a3.s[2 * m])) * inv;
    float v1 = (bf2f(a0.s[2 * m + 1]) + bf2f(a1.s[2 * m + 1]) + bf2f(a2.s[2 * m + 1]) +
                bf2f(a3.s[2 * m + 1])) * inv;
    ow[m] = cvtpk(v0, v1);
  }
  *reinterpret_cast<uint4*>(pO0 + base) = o.u;
}

// ---------------- per-row LN stats of proj (coalesced) ----------------
__global__ void k_stats(const float* __restrict__ proj, float* __restrict__ musig) {
  int w = threadIdx.x >> 6, lane = threadIdx.x & 63;
  int row = blockIdx.x * 4 + w;
  const float* pr = proj + (size_t)row * CDIM;
  const float4* p4 = reinterpret_cast<const float4*>(pr + lane * 8);
  float4 a = p4[0], bq = p4[1];
  float s = a.x + a.y + a.z + a.w + bq.x + bq.y + bq.z + bq.w;
  float s2 = a.x * a.x + a.y * a.y + a.z * a.z + a.w * a.w +
             bq.x * bq.x + bq.y * bq.y + bq.z * bq.z + bq.w * bq.w;
  for (int o = 32; o; o >>= 1) { s += __shfl_xor(s, o); s2 += __shfl_xor(s2, o); }
  if (lane == 0) {
    float mu = s * (1.0f / 512.0f);
    float var = s2 * (1.0f / 512.0f) - mu * mu;
    musig[row] = mu;
    musig[4 * NSEQ + row] = rsqrtf(var + 1e-5f);
  }
}

// ---------------- final LN + residual, LDS-transposed, fully coalesced ------
__global__ void k_final2(const float* __restrict__ proj, const float* __restrict__ musig,
                         const float* __restrict__ g, const float* __restrict__ x,
                         float* __restrict__ y) {
  int i0 = blockIdx.x * 32, c0 = blockIdx.y * 64, b = blockIdx.z;
  int t = threadIdx.x;
  __shared__ float lds[32][65];
  {
    int il = t >> 3, cB = (t & 7) * 8;
    const float4* src = reinterpret_cast<const float4*>(
        proj + (size_t)(b * NSEQ + i0 + il) * CDIM + c0 + cB);
    float4 v0 = src[0], v1 = src[1];
    *reinterpret_cast<float4*>(&lds[il][cB]) = v0;
    *reinterpret_cast<float4*>(&lds[il][cB + 4]) = v1;
  }
  __syncthreads();
  int ii = t & 31, cg = t >> 5;
  float mu = musig[b * NSEQ + i0 + ii];
  float rs = musig[4 * NSEQ + b * NSEQ + i0 + ii];
  const float* xb = x + (size_t)b * CDIM * NSEQ;
  float* yb = y + (size_t)b * CDIM * NSEQ;
#pragma unroll
  for (int cc = 0; cc < 8; cc++) {
    int cl = cg * 8 + cc;
    int c = c0 + cl;
    float v = lds[ii][cl];
    yb[(size_t)c * NSEQ + i0 + ii] = xb[(size_t)c * NSEQ + i0 + ii] + (v - mu) * rs * g[c];
  }
}

extern "C" void kernel_launch(void* const* d_in, const int* in_sizes, int n_in,
                              void* d_out, int out_size, void* d_ws, size_t ws_size,
                              hipStream_t stream) {
  const float* x       = (const float*)d_in[0];
  const float* context = (const float*)d_in[1];
  const float* ngamma  = (const float*)d_in[2];
  const float* null_kv = (const float*)d_in[3];
  const float* Wq      = (const float*)d_in[4];
  const float* Wkv     = (const float*)d_in[5];
  const float* clng    = (const float*)d_in[6];
  const float* clnb    = (const float*)d_in[7];
  const float* Wctx    = (const float*)d_in[8];
  const float* bctx    = (const float*)d_in[9];
  const float* Wout    = (const float*)d_in[10];
  const float* olng    = (const float*)d_in[11];
  float* y = (float*)d_out;
  char* ws = (char*)d_ws;

  unsigned short* xn    = (unsigned short*)(ws);              // 9437184 B (pO1 during attn)
  unsigned short* qb    = (unsigned short*)(ws + 9437184);    // 9437184 B
  float* proj           = (float*)(ws);                       // aliases xn+qb (dead by then)
  unsigned short* aoutb = (unsigned short*)(ws + 18874368);   // 9437184 B (pO0 -> merged)
  float* musig          = (float*)(ws + 18874368);            // aliases aoutb (dead after gemm1)
  unsigned short* kb    = (unsigned short*)(ws + 28311552);   // 1245184 B
  unsigned short* vtb   = (unsigned short*)(ws + 29556736);   // 1245184 B
  unsigned short* WqT   = (unsigned short*)(ws + 30801920);   // 524288 B
  unsigned short* WkvT  = (unsigned short*)(ws + 31326208);   // 131072 B
  unsigned short* WctxT = (unsigned short*)(ws + 31457280);   // 196608 B
  unsigned short* WoutT = (unsigned short*)(ws + 31653888);   // 524288 B
  // bf16 l-partials: 4 x 73728 x 2B = 589824 B, overlay WqT+WkvT (dead after gemm0)
  unsigned short* lpart = (unsigned short*)(ws + 30801920);
  // partials 2,3 live in d_out (18874368 B = exactly 2 bf16 partials);
  // k_final2 fully rewrites y afterward.
  unsigned short* pO2   = (unsigned short*)d_out;
  unsigned short* pO3   = (unsigned short*)d_out + 4718592;

  k_prep<<<dim3(2688), dim3(256), 0, stream>>>(Wq, Wkv, Wctx, Wout, WqT, WkvT, WctxT, WoutT);
  k_ln1<<<dim3(72, 4), dim3(256), 0, stream>>>(x, ngamma, xn);
  k_ctx<<<dim3(128, 4), dim3(128), 0, stream>>>(context, clng, clnb, WctxT, bctx, null_kv, kb, vtb);
  k_gemm<0><<<dim3(72, 5), dim3(256), 0, stream>>>(xn, WqT, WkvT, qb, kb, vtb, nullptr);
  k_attn<<<dim3(288, 2, 4), dim3(256), 0, stream>>>(qb, kb, vtb, aoutb, xn, pO2, pO3, lpart);
  k_merge<<<dim3(2304), dim3(256), 0, stream>>>(aoutb, xn, pO2, pO3, lpart);
  k_gemm<1><<<dim3(72, 4), dim3(256), 0, stream>>>(aoutb, WoutT, nullptr, nullptr, nullptr, nullptr, proj);
  k_stats<<<dim3(2304), dim3(256), 0, stream>>>(proj, musig);
  k_final2<<<dim3(72, 8, 4), dim3(256), 0, stream>>>(proj, musig, olng, x, y);
}

// Round 13
// 193.031 us; speedup vs baseline: 2.8724x; 1.0198x over previous
//
#include <hip/hip_runtime.h>

typedef __attribute__((ext_vector_type(8))) short bf16x8;
typedef __attribute__((ext_vector_type(4))) float f32x4;

#define LPAD 2432
#define LKV  2382
#define NSEQ 2304
#define CDIM 512
#define LPSZ (4 * NSEQ * 8)  // l-partial entries per split (rows*heads)

__device__ __forceinline__ unsigned short f2bf(float f) {
  unsigned int u = __builtin_bit_cast(unsigned int, f);
  u += 0x7fffu + ((u >> 16) & 1u);
  return (unsigned short)(u >> 16);
}
__device__ __forceinline__ float bf2f(unsigned short s) {
  unsigned int u = ((unsigned int)s) << 16;
  return __builtin_bit_cast(float, u);
}
__device__ __forceinline__ f32x4 MFMA(bf16x8 a, bf16x8 b, f32x4 c) {
  return __builtin_amdgcn_mfma_f32_16x16x32_bf16(a, b, c, 0, 0, 0);
}
__device__ __forceinline__ void stage16(const unsigned short* g, unsigned short* l) {
  __builtin_amdgcn_global_load_lds((const __attribute__((address_space(1))) void*)g,
                                   (__attribute__((address_space(3))) void*)l, 16, 0, 0);
}
__device__ __forceinline__ unsigned int cvtpk(float a, float b) {
  unsigned int r;
  asm("v_cvt_pk_bf16_f32 %0, %1, %2" : "=v"(r) : "v"(a), "v"(b));
  return r;
}
// interleaved V^T column position within each 32-chunk
__device__ __forceinline__ int Fj(int j) {
  return (j & ~31) | ((j & 15) << 1) | ((j >> 4) & 1);
}

// ---------------- weight transpose + bf16 convert ----------------
__global__ void k_prep(const float* __restrict__ Wq, const float* __restrict__ Wkv,
                       const float* __restrict__ Wctx, const float* __restrict__ Wout,
                       unsigned short* __restrict__ WqT, unsigned short* __restrict__ WkvT,
                       unsigned short* __restrict__ WctxT, unsigned short* __restrict__ WoutT) {
  int idx = blockIdx.x * 256 + threadIdx.x;
  if (idx < 262144) {
    int n = idx >> 9, k = idx & 511;
    WqT[idx] = f2bf(Wq[k * 512 + n]);
  } else if ((idx -= 262144) < 65536) {
    int n = idx >> 9, k = idx & 511;
    WkvT[idx] = f2bf(Wkv[k * 128 + n]);
  } else if ((idx -= 65536) < 98304) {
    int n = idx / 768, k = idx - n * 768;
    WctxT[idx] = f2bf(Wctx[k * 128 + n]);
  } else {
    idx -= 98304;
    int n = idx >> 9, k = idx & 511;
    WoutT[idx] = f2bf(Wout[k * 512 + n]);
  }
}

// ---------------- LN over C of x (B,C,N) -> xn bf16 (B*N, C) ----------------
__global__ void k_ln1(const float* __restrict__ x, const float* __restrict__ g,
                      unsigned short* __restrict__ xn) {
  int b = blockIdx.y;
  int i0 = blockIdx.x * 32;
  int t = threadIdx.x;
  int ii = t & 31, ci = t >> 5;
  const float* xb = x + (size_t)b * CDIM * NSEQ;
  float s = 0.f, s2 = 0.f;
  for (int c = ci; c < CDIM; c += 8) {
    float v = xb[(size_t)c * NSEQ + i0 + ii];
    s += v; s2 += v * v;
  }
  __shared__ float ls[8][32], ls2[8][32];
  __shared__ float lmu[32], lrs[32];
  ls[ci][ii] = s; ls2[ci][ii] = s2;
  __syncthreads();
  if (t < 32) {
    float a = 0.f, a2 = 0.f;
    for (int q = 0; q < 8; q++) { a += ls[q][t]; a2 += ls2[q][t]; }
    float mu = a * (1.0f / 512.0f);
    float var = a2 * (1.0f / 512.0f) - mu * mu;
    lmu[t] = mu; lrs[t] = rsqrtf(var + 1e-5f);
  }
  __syncthreads();
  float mu = lmu[ii], rs = lrs[ii];
  unsigned short* xrow = xn + (size_t)(b * NSEQ + i0 + ii) * CDIM;
  for (int c = ci; c < CDIM; c += 8) {
    float v = xb[(size_t)c * NSEQ + i0 + ii];
    xrow[c] = f2bf((v - mu) * rs * g[c]);
  }
}

// ---------------- context LN + projection; null row + zero pads ----------
__global__ void k_ctx(const float* __restrict__ ctx, const float* __restrict__ g,
                      const float* __restrict__ be, const unsigned short* __restrict__ WctxT,
                      const float* __restrict__ bctx, const float* __restrict__ null_kv,
                      unsigned short* __restrict__ kb, unsigned short* __restrict__ vt) {
  int b = blockIdx.y, j = blockIdx.x;
  int t = threadIdx.x;
  if (j == 77) {
    if (t < 64) kb[((size_t)b * LPAD + 77) * 64 + t] = f2bf(null_kv[t]);
    else vt[((size_t)b * 64 + (t - 64)) * LPAD + Fj(77)] = f2bf(null_kv[64 + (t - 64)]);
    return;
  }
  if (j > 77) {
    int jj = LKV + (j - 78);
    if (t < 64) kb[((size_t)b * LPAD + jj) * 64 + t] = 0;
    else vt[((size_t)b * 64 + (t - 64)) * LPAD + Fj(jj)] = 0;
    return;
  }
  __shared__ float row[768];
  __shared__ float red[4];
  const float* src = ctx + (size_t)(b * 77 + j) * 768;
  float s = 0.f, s2 = 0.f;
  for (int k = t; k < 768; k += 128) {
    float v = src[k];
    row[k] = v; s += v; s2 += v * v;
  }
  for (int o = 32; o; o >>= 1) { s += __shfl_xor(s, o); s2 += __shfl_xor(s2, o); }
  if ((t & 63) == 0) { red[(t >> 6) * 2] = s; red[(t >> 6) * 2 + 1] = s2; }
  __syncthreads();
  float S = red[0] + red[2], S2 = red[1] + red[3];
  float mu = S * (1.0f / 768.0f);
  float rs = rsqrtf(S2 * (1.0f / 768.0f) - mu * mu + 1e-5f);
  __syncthreads();
  for (int k = t; k < 768; k += 128) row[k] = (row[k] - mu) * rs * g[k] + be[k];
  __syncthreads();
  const uint4* w4 = reinterpret_cast<const uint4*>(WctxT + (size_t)t * 768);
  float acc = 0.f;
  for (int k8 = 0; k8 < 96; k8++) {
    union { uint4 u; unsigned short s[8]; } wv;
    wv.u = w4[k8];
#pragma unroll
    for (int e = 0; e < 8; e++) acc += row[k8 * 8 + e] * bf2f(wv.s[e]);
  }
  acc += bctx[t];
  if (t < 64) kb[((size_t)b * LPAD + j) * 64 + t] = f2bf(acc);
  else vt[((size_t)b * 64 + (t - 64)) * LPAD + Fj(j)] = f2bf(acc);
}

// ---------------- MFMA GEMM ----------------
template <int MODE>
__global__ __launch_bounds__(256, 1) void k_gemm(
    const unsigned short* __restrict__ A, const unsigned short* __restrict__ BT0,
    const unsigned short* __restrict__ BT1, unsigned short* __restrict__ out_q,
    unsigned short* __restrict__ out_k, unsigned short* __restrict__ out_vt,
    float* __restrict__ out_proj) {
  int m0 = blockIdx.x * 128, n0 = blockIdx.y * 128;
  int t = threadIdx.x;
  int lane = t & 63, w = t >> 6;
  int wm = w >> 1, wn = w & 1;
  int G = lane >> 4, li = lane & 15;
  __shared__ unsigned short Al[128][72];
  __shared__ unsigned short Bl[128][72];
  const unsigned short* BT = (MODE == 0 && n0 >= 512) ? BT1 : BT0;
  int bn0 = (MODE == 0 && n0 >= 512) ? n0 - 512 : n0;
  f32x4 zero = {0.f, 0.f, 0.f, 0.f};
  f32x4 acc[4][4];
#pragma unroll
  for (int a = 0; a < 4; a++)
#pragma unroll
    for (int c = 0; c < 4; c++) acc[a][c] = zero;
  int sr = t >> 1, sc = (t & 1) * 32;
  for (int k0 = 0; k0 < 512; k0 += 64) {
    const uint4* sA = reinterpret_cast<const uint4*>(A + (size_t)(m0 + sr) * 512 + k0 + sc);
    const uint4* sB = reinterpret_cast<const uint4*>(BT + (size_t)(bn0 + sr) * 512 + k0 + sc);
    uint4 a0 = sA[0], a1 = sA[1], a2 = sA[2], a3 = sA[3];
    uint4 b0 = sB[0], b1 = sB[1], b2 = sB[2], b3 = sB[3];
    uint4* dA = reinterpret_cast<uint4*>(&Al[sr][sc]);
    uint4* dB = reinterpret_cast<uint4*>(&Bl[sr][sc]);
    dA[0] = a0; dA[1] = a1; dA[2] = a2; dA[3] = a3;
    dB[0] = b0; dB[1] = b1; dB[2] = b2; dB[3] = b3;
    __syncthreads();
#pragma unroll
    for (int ks = 0; ks < 2; ks++) {
      bf16x8 af[4], bfr[4];
#pragma unroll
      for (int f = 0; f < 4; f++) {
        af[f] = *reinterpret_cast<const bf16x8*>(&Al[wm * 64 + f * 16 + li][ks * 32 + G * 8]);
        bfr[f] = *reinterpret_cast<const bf16x8*>(&Bl[wn * 64 + f * 16 + li][ks * 32 + G * 8]);
      }
#pragma unroll
      for (int fm = 0; fm < 4; fm++)
#pragma unroll
        for (int fn = 0; fn < 4; fn++)
          acc[fm][fn] = MFMA(af[fm], bfr[fn], acc[fm][fn]);
    }
    __syncthreads();
  }
#pragma unroll
  for (int fm = 0; fm < 4; fm++)
#pragma unroll
    for (int fn = 0; fn < 4; fn++)
#pragma unroll
      for (int r = 0; r < 4; r++) {
        int row = m0 + wm * 64 + fm * 16 + G * 4 + r;
        int col = n0 + wn * 64 + fn * 16 + li;
        float v = acc[fm][fn][r];
        if (MODE == 0) {
          int b = row / NSEQ, i = row - b * NSEQ;
          // q pre-scaled by 1/sqrt(dh) * log2(e): softmax runs in exp2 domain
          if (col < 512) out_q[(size_t)row * 512 + col] = f2bf(v * 0.18033688011112042f);
          else if (col < 576) out_k[((size_t)b * LPAD + 78 + i) * 64 + (col - 512)] = f2bf(v);
          else out_vt[((size_t)b * 64 + (col - 576)) * LPAD + Fj(78 + i)] = f2bf(v);
        } else {
          out_proj[(size_t)row * 512 + col] = v;
        }
      }
}

// ---------------- flash attention: 4-way KV split, KVBLK=32, 16KB LDS -------
// Residency theory: 32KB LDS pinned us at 2 blocks/CU (~26% occupancy in
// R9/R12 regardless of supply/VGPR). KVBLK=32 -> K tile 32jx64d (4KB) +
// V^T tile 64dx32j (4KB), double-buffered = 16KB -> 4 blocks/CU.
// 76 tiles of 32 rows, 19 per split (exact). One stage16/thread/buffer.
// V granule swizzle (li ^ (li>>2))&3: rows li,li+4,li+8,li+12 share a bank
// window at 64B row stride; plain &3 would be 4-way conflicted.
__global__ __launch_bounds__(256, 4) void k_attn(
    const unsigned short* __restrict__ q, const unsigned short* __restrict__ kbuf,
    const unsigned short* __restrict__ vt, unsigned short* __restrict__ pO0,
    unsigned short* __restrict__ pO1, unsigned short* __restrict__ pO2,
    unsigned short* __restrict__ pO3, unsigned short* __restrict__ lp) {
  int bx = blockIdx.x;
  int it = bx >> 2, sp = bx & 3;
  int hh = blockIdx.y, b = blockIdx.z;
  int i0 = it * 32;
  int t = threadIdx.x;
  int w = t >> 6, lane = t & 63;
  int G = lane >> 4, li = lane & 15, li7 = lane & 7;
  int swzV = (li ^ (li >> 2)) & 3;
  int h = hh * 4 + w;

  __shared__ __align__(16) unsigned short Kl[2][2048];  // 32 rows x 64 d (4KB)
  __shared__ __align__(16) unsigned short Vl[2][2048];  // 64 rows x 32 j (4KB)

  // K staging: row rk = t>>3 (0..31), 8-granule col swizzled by row&7
  int rk = t >> 3;
  int ck = ((t & 7) ^ (rk & 7)) * 8;
  // V staging: row rv = t>>2 (0..63), 4-granule col swizzled by (rv^(rv>>2))&3
  int rv = t >> 2;
  int cv = ((t & 3) ^ ((rv ^ (rv >> 2)) & 3)) * 8;

  const unsigned short* kbase = kbuf + (size_t)b * LPAD * 64;
  const unsigned short* vbase = vt + (size_t)b * 64 * LPAD;

  bf16x8 qf[2][2];
#pragma unroll
  for (int fi = 0; fi < 2; fi++)
#pragma unroll
    for (int ks = 0; ks < 2; ks++)
      qf[fi][ks] = *reinterpret_cast<const bf16x8*>(
          q + (size_t)(b * NSEQ + i0 + fi * 16 + li) * CDIM + h * 64 + ks * 32 + G * 8);

  int jt0 = sp * 19;  // 76 tiles of 32 / 4 splits = 19 exact

  // stage first tile of this split into buffer [0]
  {
    int j0 = jt0 * 32;
    stage16(kbase + (size_t)(j0 + rk) * 64 + ck, &Kl[0][w * 512]);
    stage16(vbase + (size_t)rv * LPAD + j0 + cv, &Vl[0][w * 512]);
  }

  f32x4 zero = {0.f, 0.f, 0.f, 0.f};
  f32x4 OT[4][2];  // [fd][fi]; row d = fd*16+G*4+r, col i = fi*16+li
#pragma unroll
  for (int fd = 0; fd < 4; fd++)
#pragma unroll
    for (int fi = 0; fi < 2; fi++) OT[fd][fi] = zero;
  float l_[2] = {0.f, 0.f};

  __syncthreads();

  for (int u = 0; u < 19; u++) {
    int jt = jt0 + u;
    int cur = u & 1, nxt = cur ^ 1;  // LOCAL parity
    int j0 = jt * 32;
    if (u + 1 < 19) {
      int j1 = j0 + 32;
      stage16(kbase + (size_t)(j1 + rk) * 64 + ck, &Kl[nxt][w * 512]);
      stage16(vbase + (size_t)rv * LPAD + j1 + cv, &Vl[nxt][w * 512]);
    }
    const char* Kc = (const char*)Kl[cur];
    const char* Vc = (const char*)Vl[cur];

    f32x4 S[2][2];
#pragma unroll
    for (int fj = 0; fj < 2; fj++) { S[fj][0] = zero; S[fj][1] = zero; }
#pragma unroll
    for (int ks = 0; ks < 2; ks++) {
      bf16x8 kf[2];
#pragma unroll
      for (int fj = 0; fj < 2; fj++)
        kf[fj] = *reinterpret_cast<const bf16x8*>(
            Kc + ((((fj * 16 + li) * 8) + ((ks * 4 + G) ^ li7)) << 4));
#pragma unroll
      for (int fj = 0; fj < 2; fj++)
#pragma unroll
        for (int fi = 0; fi < 2; fi++)
          S[fj][fi] = MFMA(kf[fj], qf[fi][ks], S[fj][fi]);
    }
    if (j0 + 32 > LKV) {
#pragma unroll
      for (int fj = 0; fj < 2; fj++)
#pragma unroll
        for (int r = 0; r < 4; r++) {
          int jg = j0 + fj * 16 + G * 4 + r;
          if (jg >= LKV) { S[fj][0][r] = -1e30f; S[fj][1][r] = -1e30f; }
        }
    }
    // no-max softmax: e = exp2(S); pack pf in interleaved-j bijection:
    // B k-slot (G,E) <-> j = (E&1)*16 + G*4 + (E>>1)
    bf16x8 pf[2];
#pragma unroll
    for (int fi = 0; fi < 2; fi++) {
      float e[2][4];
#pragma unroll
      for (int fj = 0; fj < 2; fj++)
#pragma unroll
        for (int r = 0; r < 4; r++) e[fj][r] = __builtin_exp2f(S[fj][fi][r]);
      float s0 = (e[0][0] + e[0][1]) + (e[0][2] + e[0][3]);
      float s1 = (e[1][0] + e[1][1]) + (e[1][2] + e[1][3]);
      l_[fi] += s0 + s1;
      union { unsigned int w4[4]; bf16x8 v; } u2;
#pragma unroll
      for (int m = 0; m < 4; m++) u2.w4[m] = cvtpk(e[0][m], e[1][m]);
      pf[fi] = u2.v;
    }
    // PV from LDS V^T (interleaved layout): one b128 per fd
#pragma unroll
    for (int fd = 0; fd < 4; fd++) {
      bf16x8 uv = *reinterpret_cast<const bf16x8*>(
          Vc + (((fd * 16 + li) * 4 + (G ^ swzV)) << 4));
#pragma unroll
      for (int fi = 0; fi < 2; fi++) OT[fd][fi] = MFMA(uv, pf[fi], OT[fd][fi]);
    }
    __syncthreads();
  }

  // write unnormalized partials + bf16 l partials
  unsigned short* pO = (sp == 0) ? pO0 : (sp == 1) ? pO1 : (sp == 2) ? pO2 : pO3;
#pragma unroll
  for (int fi = 0; fi < 2; fi++) {
    l_[fi] += __shfl_xor(l_[fi], 16);
    l_[fi] += __shfl_xor(l_[fi], 32);
    int row = b * NSEQ + i0 + fi * 16 + li;
    if (G == 0) lp[sp * LPSZ + row * 8 + h] = f2bf(l_[fi]);
#pragma unroll
    for (int fd = 0; fd < 4; fd++) {
      union { unsigned int w2[2]; uint2 u2; } pk;
      pk.w2[0] = cvtpk(OT[fd][fi][0], OT[fd][fi][1]);
      pk.w2[1] = cvtpk(OT[fd][fi][2], OT[fd][fi][3]);
      *reinterpret_cast<uint2*>(pO + (size_t)row * CDIM + h * 64 + fd * 16 + G * 4) = pk.u2;
    }
  }
}

// ---------------- merge the four KV-split partials ----------------
// out (in place over pO0) = (O0+O1+O2+O3) / (l0+l1+l2+l3), bf16
__global__ void k_merge(unsigned short* __restrict__ pO0,
                        const unsigned short* __restrict__ pO1,
                        const unsigned short* __restrict__ pO2,
                        const unsigned short* __restrict__ pO3,
                        const unsigned short* __restrict__ lp) {
  int c = blockIdx.x * 256 + threadIdx.x;  // 16B chunk index (8 bf16)
  size_t base = (size_t)c * 8;
  int row = (int)(base >> 9);
  int h = (int)((base >> 6) & 7);
  int li = row * 8 + h;
  float l = bf2f(lp[li]) + bf2f(lp[LPSZ + li]) + bf2f(lp[2 * LPSZ + li]) + bf2f(lp[3 * LPSZ + li]);
  float inv = 1.0f / l;
  union { uint4 u; unsigned short s[8]; } a0, a1, a2, a3, o;
  a0.u = *reinterpret_cast<const uint4*>(pO0 + base);
  a1.u = *reinterpret_cast<const uint4*>(pO1 + base);
  a2.u = *reinterpret_cast<const uint4*>(pO2 + base);
  a3.u = *reinterpret_cast<const uint4*>(pO3 + base);
  unsigned int* ow = reinterpret_cast<unsigned int*>(&o.u);
#pragma unroll
  for (int m = 0; m < 4; m++) {
    float v0 = (bf2f(a0.s[2 * m]) + bf2f(a1.s[2 * m]) + bf2f(a2.s[2 * m]) + bf2f(a3.s[2 * m])) * inv;
    float v1 = (bf2f(a0.s[2 * m + 1]) + bf2f(a1.s[2 * m + 1]) + bf2f(a2.s[2 * m + 1]) +
                bf2f(a3.s[2 * m + 1])) * inv;
    ow[m] = cvtpk(v0, v1);
  }
  *reinterpret_cast<uint4*>(pO0 + base) = o.u;
}

// ---------------- per-row LN stats of proj (coalesced) ----------------
__global__ void k_stats(const float* __restrict__ proj, float* __restrict__ musig) {
  int w = threadIdx.x >> 6, lane = threadIdx.x & 63;
  int row = blockIdx.x * 4 + w;
  const float* pr = proj + (size_t)row * CDIM;
  const float4* p4 = reinterpret_cast<const float4*>(pr + lane * 8);
  float4 a = p4[0], bq = p4[1];
  float s = a.x + a.y + a.z + a.w + bq.x + bq.y + bq.z + bq.w;
  float s2 = a.x * a.x + a.y * a.y + a.z * a.z + a.w * a.w +
             bq.x * bq.x + bq.y * bq.y + bq.z * bq.z + bq.w * bq.w;
  for (int o = 32; o; o >>= 1) { s += __shfl_xor(s, o); s2 += __shfl_xor(s2, o); }
  if (lane == 0) {
    float mu = s * (1.0f / 512.0f);
    float var = s2 * (1.0f / 512.0f) - mu * mu;
    musig[row] = mu;
    musig[4 * NSEQ + row] = rsqrtf(var + 1e-5f);
  }
}

// ---------------- final LN + residual, LDS-transposed, fully coalesced ------
__global__ void k_final2(const float* __restrict__ proj, const float* __restrict__ musig,
                         const float* __restrict__ g, const float* __restrict__ x,
                         float* __restrict__ y) {
  int i0 = blockIdx.x * 32, c0 = blockIdx.y * 64, b = blockIdx.z;
  int t = threadIdx.x;
  __shared__ float lds[32][65];
  {
    int il = t >> 3, cB = (t & 7) * 8;
    const float4* src = reinterpret_cast<const float4*>(
        proj + (size_t)(b * NSEQ + i0 + il) * CDIM + c0 + cB);
    float4 v0 = src[0], v1 = src[1];
    *reinterpret_cast<float4*>(&lds[il][cB]) = v0;
    *reinterpret_cast<float4*>(&lds[il][cB + 4]) = v1;
  }
  __syncthreads();
  int ii = t & 31, cg = t >> 5;
  float mu = musig[b * NSEQ + i0 + ii];
  float rs = musig[4 * NSEQ + b * NSEQ + i0 + ii];
  const float* xb = x + (size_t)b * CDIM * NSEQ;
  float* yb = y + (size_t)b * CDIM * NSEQ;
#pragma unroll
  for (int cc = 0; cc < 8; cc++) {
    int cl = cg * 8 + cc;
    int c = c0 + cl;
    float v = lds[ii][cl];
    yb[(size_t)c * NSEQ + i0 + ii] = xb[(size_t)c * NSEQ + i0 + ii] + (v - mu) * rs * g[c];
  }
}

extern "C" void kernel_launch(void* const* d_in, const int* in_sizes, int n_in,
                              void* d_out, int out_size, void* d_ws, size_t ws_size,
                              hipStream_t stream) {
  const float* x       = (const float*)d_in[0];
  const float* context = (const float*)d_in[1];
  const float* ngamma  = (const float*)d_in[2];
  const float* null_kv = (const float*)d_in[3];
  const float* Wq      = (const float*)d_in[4];
  const float* Wkv     = (const float*)d_in[5];
  const float* clng    = (const float*)d_in[6];
  const float* clnb    = (const float*)d_in[7];
  const float* Wctx    = (const float*)d_in[8];
  const float* bctx    = (const float*)d_in[9];
  const float* Wout    = (const float*)d_in[10];
  const float* olng    = (const float*)d_in[11];
  float* y = (float*)d_out;
  char* ws = (char*)d_ws;

  unsigned short* xn    = (unsigned short*)(ws);              // 9437184 B (pO1 during attn)
  unsigned short* qb    = (unsigned short*)(ws + 9437184);    // 9437184 B
  float* proj           = (float*)(ws);                       // aliases xn+qb (dead by then)
  unsigned short* aoutb = (unsigned short*)(ws + 18874368);   // 9437184 B (pO0 -> merged)
  float* musig          = (float*)(ws + 18874368);            // aliases aoutb (dead after gemm1)
  unsigned short* kb    = (unsigned short*)(ws + 28311552);   // 1245184 B
  unsigned short* vtb   = (unsigned short*)(ws + 29556736);   // 1245184 B
  unsigned short* WqT   = (unsigned short*)(ws + 30801920);   // 524288 B
  unsigned short* WkvT  = (unsigned short*)(ws + 31326208);   // 131072 B
  unsigned short* WctxT = (unsigned short*)(ws + 31457280);   // 196608 B
  unsigned short* WoutT = (unsigned short*)(ws + 31653888);   // 524288 B
  // bf16 l-partials: 4 x 73728 x 2B = 589824 B, overlay WqT+WkvT (dead after gemm0)
  unsigned short* lpart = (unsigned short*)(ws + 30801920);
  // partials 2,3 live in d_out (18874368 B = exactly 2 bf16 partials);
  // k_final2 fully rewrites y afterward.
  unsigned short* pO2   = (unsigned short*)d_out;
  unsigned short* pO3   = (unsigned short*)d_out + 4718592;

  k_prep<<<dim3(2688), dim3(256), 0, stream>>>(Wq, Wkv, Wctx, Wout, WqT, WkvT, WctxT, WoutT);
  k_ln1<<<dim3(72, 4), dim3(256), 0, stream>>>(x, ngamma, xn);
  k_ctx<<<dim3(128, 4), dim3(128), 0, stream>>>(context, clng, clnb, WctxT, bctx, null_kv, kb, vtb);
  k_gemm<0><<<dim3(72, 5), dim3(256), 0, stream>>>(xn, WqT, WkvT, qb, kb, vtb, nullptr);
  k_attn<<<dim3(288, 2, 4), dim3(256), 0, stream>>>(qb, kb, vtb, aoutb, xn, pO2, pO3, lpart);
  k_merge<<<dim3(2304), dim3(256), 0, stream>>>(aoutb, xn, pO2, pO3, lpart);
  k_gemm<1><<<dim3(72, 4), dim3(256), 0, stream>>>(aoutb, WoutT, nullptr, nullptr, nullptr, nullptr, proj);
  k_stats<<<dim3(2304), dim3(256), 0, stream>>>(proj, musig);
  k_final2<<<dim3(72, 8, 4), dim3(256), 0, stream>>>(proj, musig, olng, x, y);
}

// Round 14
// 171.467 us; speedup vs baseline: 3.2337x; 1.1258x over previous
//
#include <hip/hip_runtime.h>

typedef __attribute__((ext_vector_type(8))) short bf16x8;
typedef __attribute__((ext_vector_type(4))) float f32x4;

#define LPAD 2432
#define LKV  2382
#define NSEQ 2304
#define CDIM 512
#define LPSZ (4 * NSEQ * 8)  // l-partial entries per split (rows*heads)

__device__ __forceinline__ unsigned short f2bf(float f) {
  unsigned int u = __builtin_bit_cast(unsigned int, f);
  u += 0x7fffu + ((u >> 16) & 1u);
  return (unsigned short)(u >> 16);
}
__device__ __forceinline__ float bf2f(unsigned short s) {
  unsigned int u = ((unsigned int)s) << 16;
  return __builtin_bit_cast(float, u);
}
__device__ __forceinline__ f32x4 MFMA(bf16x8 a, bf16x8 b, f32x4 c) {
  return __builtin_amdgcn_mfma_f32_16x16x32_bf16(a, b, c, 0, 0, 0);
}
__device__ __forceinline__ void stage16(const unsigned short* g, unsigned short* l) {
  __builtin_amdgcn_global_load_lds((const __attribute__((address_space(1))) void*)g,
                                   (__attribute__((address_space(3))) void*)l, 16, 0, 0);
}
__device__ __forceinline__ unsigned int cvtpk(float a, float b) {
  unsigned int r;
  asm("v_cvt_pk_bf16_f32 %0, %1, %2" : "=v"(r) : "v"(a), "v"(b));
  return r;
}
// interleaved V^T column position within each 32-chunk
__device__ __forceinline__ int Fj(int j) {
  return (j & ~31) | ((j & 15) << 1) | ((j >> 4) & 1);
}

// ---------------- weight transpose + bf16 convert (LDS tiled, coalesced) ----
// [K][N] f32 -> [N][K] bf16 via 32x32 tiles; both sides coalesced.
__device__ __forceinline__ void tr_tile(const float* __restrict__ in,
                                        unsigned short* __restrict__ out,
                                        int K, int N, int tk, int tn, int t) {
  __shared__ float T[32][33];
  int r = t >> 5, c = t & 31;
#pragma unroll
  for (int p = 0; p < 4; p++) {
    int rr = r + p * 8;
    T[rr][c] = in[(size_t)(tk * 32 + rr) * N + tn * 32 + c];
  }
  __syncthreads();
#pragma unroll
  for (int p = 0; p < 4; p++) {
    int rr = r + p * 8;
    out[(size_t)(tn * 32 + rr) * K + tk * 32 + c] = f2bf(T[c][rr]);
  }
}

__global__ void k_prep(const float* __restrict__ Wq, const float* __restrict__ Wkv,
                       const float* __restrict__ Wctx, const float* __restrict__ Wout,
                       unsigned short* __restrict__ WqT, unsigned short* __restrict__ WkvT,
                       unsigned short* __restrict__ WctxT, unsigned short* __restrict__ WoutT) {
  int bid = blockIdx.x, t = threadIdx.x;
  if (bid < 256) {            // Wq 512x512: 16x16 tiles
    tr_tile(Wq, WqT, 512, 512, bid >> 4, bid & 15, t);
  } else if (bid < 320) {     // Wkv 512x128: 16x4 tiles
    int q = bid - 256;
    tr_tile(Wkv, WkvT, 512, 128, q >> 2, q & 3, t);
  } else if (bid < 416) {     // Wctx 768x128: 24x4 tiles
    int q = bid - 320;
    tr_tile(Wctx, WctxT, 768, 128, q >> 2, q & 3, t);
  } else {                    // Wout 512x512
    int q = bid - 416;
    tr_tile(Wout, WoutT, 512, 512, q >> 4, q & 15, t);
  }
}

// ---------------- LN over C of x (B,C,N) -> xn bf16 (B*N, C) ----------------
// Phase 1: coalesced strided-C reads -> per-row stats.
// Phase 2: re-read coalesced, LN into LDS f32 [32][65] (conflict-free), then
// write 16B/thread coalesced rows (old version did 2B scattered stores).
__global__ void k_ln1(const float* __restrict__ x, const float* __restrict__ g,
                      unsigned short* __restrict__ xn) {
  int b = blockIdx.y;
  int i0 = blockIdx.x * 32;
  int t = threadIdx.x;
  int ii = t & 31, ci = t >> 5;
  const float* xb = x + (size_t)b * CDIM * NSEQ;
  float s = 0.f, s2 = 0.f;
  for (int c = ci; c < CDIM; c += 8) {
    float v = xb[(size_t)c * NSEQ + i0 + ii];
    s += v; s2 += v * v;
  }
  __shared__ float ls[8][32], ls2[8][32];
  __shared__ float lmu[32], lrs[32];
  __shared__ float Lt[32][65];
  ls[ci][ii] = s; ls2[ci][ii] = s2;
  __syncthreads();
  if (t < 32) {
    float a = 0.f, a2 = 0.f;
    for (int q = 0; q < 8; q++) { a += ls[q][t]; a2 += ls2[q][t]; }
    float mu = a * (1.0f / 512.0f);
    float var = a2 * (1.0f / 512.0f) - mu * mu;
    lmu[t] = mu; lrs[t] = rsqrtf(var + 1e-5f);
  }
  __syncthreads();
  float mu = lmu[ii], rs = lrs[ii];
  int rr = t >> 3, cl0 = (t & 7) * 8;
  for (int cb = 0; cb < 8; cb++) {
#pragma unroll
    for (int e = 0; e < 8; e++) {
      int cl = ci + 8 * e;
      int c = cb * 64 + cl;
      float v = xb[(size_t)c * NSEQ + i0 + ii];
      Lt[ii][cl] = (v - mu) * rs * g[c];
    }
    __syncthreads();
    union { unsigned int w4[4]; uint4 u; } pk;
#pragma unroll
    for (int m = 0; m < 4; m++)
      pk.w4[m] = cvtpk(Lt[rr][cl0 + 2 * m], Lt[rr][cl0 + 2 * m + 1]);
    *reinterpret_cast<uint4*>(xn + (size_t)(b * NSEQ + i0 + rr) * CDIM + cb * 64 + cl0) = pk.u;
    __syncthreads();
  }
}

// ---------------- context LN + projection; null row + zero pads ----------
__global__ void k_ctx(const float* __restrict__ ctx, const float* __restrict__ g,
                      const float* __restrict__ be, const unsigned short* __restrict__ WctxT,
                      const float* __restrict__ bctx, const float* __restrict__ null_kv,
                      unsigned short* __restrict__ kb, unsigned short* __restrict__ vt) {
  int b = blockIdx.y, j = blockIdx.x;
  int t = threadIdx.x;
  if (j == 77) {
    if (t < 64) kb[((size_t)b * LPAD + 77) * 64 + t] = f2bf(null_kv[t]);
    else vt[((size_t)b * 64 + (t - 64)) * LPAD + Fj(77)] = f2bf(null_kv[64 + (t - 64)]);
    return;
  }
  if (j > 77) {
    int jj = LKV + (j - 78);
    if (t < 64) kb[((size_t)b * LPAD + jj) * 64 + t] = 0;
    else vt[((size_t)b * 64 + (t - 64)) * LPAD + Fj(jj)] = 0;
    return;
  }
  __shared__ float row[768];
  __shared__ float red[4];
  const float* src = ctx + (size_t)(b * 77 + j) * 768;
  float s = 0.f, s2 = 0.f;
  for (int k = t; k < 768; k += 128) {
    float v = src[k];
    row[k] = v; s += v; s2 += v * v;
  }
  for (int o = 32; o; o >>= 1) { s += __shfl_xor(s, o); s2 += __shfl_xor(s2, o); }
  if ((t & 63) == 0) { red[(t >> 6) * 2] = s; red[(t >> 6) * 2 + 1] = s2; }
  __syncthreads();
  float S = red[0] + red[2], S2 = red[1] + red[3];
  float mu = S * (1.0f / 768.0f);
  float rs = rsqrtf(S2 * (1.0f / 768.0f) - mu * mu + 1e-5f);
  __syncthreads();
  for (int k = t; k < 768; k += 128) row[k] = (row[k] - mu) * rs * g[k] + be[k];
  __syncthreads();
  const uint4* w4 = reinterpret_cast<const uint4*>(WctxT + (size_t)t * 768);
  float acc = 0.f;
  for (int k8 = 0; k8 < 96; k8++) {
    union { uint4 u; unsigned short s[8]; } wv;
    wv.u = w4[k8];
#pragma unroll
    for (int e = 0; e < 8; e++) acc += row[k8 * 8 + e] * bf2f(wv.s[e]);
  }
  acc += bctx[t];
  if (t < 64) kb[((size_t)b * LPAD + j) * 64 + t] = f2bf(acc);
  else vt[((size_t)b * 64 + (t - 64)) * LPAD + Fj(j)] = f2bf(acc);
}

// ---------------- MFMA GEMM: BM=128 BN=64 BK=64, global_load_lds + dbuf -----
// 4 waves (wm 2 x wn 2), wave computes 64x32. Staging: one 16B granule/lane,
// source-side XOR swizzle (granule col ^= row&7), LDS linear; frag reads
// apply the same XOR (row&7 == li&7 since all row offsets are mult of 8).
template <int MODE>
__global__ __launch_bounds__(256, 1) void k_gemm(
    const unsigned short* __restrict__ A, const unsigned short* __restrict__ BT0,
    const unsigned short* __restrict__ BT1, unsigned short* __restrict__ out_q,
    unsigned short* __restrict__ out_k, unsigned short* __restrict__ out_vt,
    float* __restrict__ out_proj) {
  int m0 = blockIdx.x * 128, n0 = blockIdx.y * 64;
  int t = threadIdx.x;
  int lane = t & 63, w = t >> 6;
  int wm = w >> 1, wn = w & 1;
  int G = lane >> 4, li = lane & 15, li7 = lane & 7;
  __shared__ __align__(16) unsigned short Al[2][8192];  // 128 x 64
  __shared__ __align__(16) unsigned short Bl[2][4096];  // 64 x 64
  const unsigned short* BT = (MODE == 0 && n0 >= 512) ? BT1 : BT0;
  int bn0 = (MODE == 0 && n0 >= 512) ? n0 - 512 : n0;

  f32x4 zero = {0.f, 0.f, 0.f, 0.f};
  f32x4 acc[4][2];
#pragma unroll
  for (int a = 0; a < 4; a++)
#pragma unroll
    for (int c = 0; c < 2; c++) acc[a][c] = zero;

  // staging geometry (per thread): A granules t+256p (p<4), B granules t+256p (p<2)
  // granule g -> row g>>3, swizzled col16 (g&7)^(row&7)
#define STAGE_AB(buf, k0)                                                              \
  {                                                                                    \
    _Pragma("unroll") for (int p = 0; p < 4; p++) {                                    \
      int gA = p * 256 + t;                                                            \
      int ra = gA >> 3;                                                                \
      int ca = ((gA & 7) ^ (ra & 7)) * 8;                                              \
      stage16(A + (size_t)(m0 + ra) * 512 + (k0) + ca, &Al[buf][(p * 256 + w * 64) * 8]); \
    }                                                                                  \
    _Pragma("unroll") for (int p = 0; p < 2; p++) {                                    \
      int gB = p * 256 + t;                                                            \
      int rb = gB >> 3;                                                                \
      int cb = ((gB & 7) ^ (rb & 7)) * 8;                                              \
      stage16(BT + (size_t)(bn0 + rb) * 512 + (k0) + cb, &Bl[buf][(p * 256 + w * 64) * 8]); \
    }                                                                                  \
  }

  STAGE_AB(0, 0)
  __syncthreads();

  for (int u = 0; u < 8; u++) {
    int cur = u & 1, nxt = cur ^ 1;
    if (u < 7) STAGE_AB(nxt, (u + 1) * 64)
    const char* Ac = (const char*)Al[cur];
    const char* Bc = (const char*)Bl[cur];
#pragma unroll
    for (int ks = 0; ks < 2; ks++) {
      bf16x8 af[4], bfr[2];
#pragma unroll
      for (int f = 0; f < 4; f++)
        af[f] = *reinterpret_cast<const bf16x8*>(
            Ac + ((((wm * 64 + f * 16 + li) * 8) + ((ks * 4 + G) ^ li7)) << 4));
#pragma unroll
      for (int f = 0; f < 2; f++)
        bfr[f] = *reinterpret_cast<const bf16x8*>(
            Bc + ((((wn * 32 + f * 16 + li) * 8) + ((ks * 4 + G) ^ li7)) << 4));
#pragma unroll
      for (int fm = 0; fm < 4; fm++)
#pragma unroll
        for (int fn = 0; fn < 2; fn++)
          acc[fm][fn] = MFMA(af[fm], bfr[fn], acc[fm][fn]);
    }
    __syncthreads();
  }
#undef STAGE_AB

#pragma unroll
  for (int fm = 0; fm < 4; fm++)
#pragma unroll
    for (int fn = 0; fn < 2; fn++)
#pragma unroll
      for (int r = 0; r < 4; r++) {
        int row = m0 + wm * 64 + fm * 16 + G * 4 + r;
        int col = n0 + wn * 32 + fn * 16 + li;
        float v = acc[fm][fn][r];
        if (MODE == 0) {
          int b = row / NSEQ, i = row - b * NSEQ;
          // q pre-scaled by 1/sqrt(dh) * log2(e): softmax runs in exp2 domain
          if (col < 512) out_q[(size_t)row * 512 + col] = f2bf(v * 0.18033688011112042f);
          else if (col < 576) out_k[((size_t)b * LPAD + 78 + i) * 64 + (col - 512)] = f2bf(v);
          else out_vt[((size_t)b * 64 + (col - 576)) * LPAD + Fj(78 + i)] = f2bf(v);
        } else {
          out_proj[(size_t)row * 512 + col] = v;
        }
      }
}

// ---------------- flash attention: 4-way KV split, KVBLK=32, 16KB LDS -------
__global__ __launch_bounds__(256, 4) void k_attn(
    const unsigned short* __restrict__ q, const unsigned short* __restrict__ kbuf,
    const unsigned short* __restrict__ vt, unsigned short* __restrict__ pO0,
    unsigned short* __restrict__ pO1, unsigned short* __restrict__ pO2,
    unsigned short* __restrict__ pO3, unsigned short* __restrict__ lp) {
  int bx = blockIdx.x;
  int it = bx >> 2, sp = bx & 3;
  int hh = blockIdx.y, b = blockIdx.z;
  int i0 = it * 32;
  int t = threadIdx.x;
  int w = t >> 6, lane = t & 63;
  int G = lane >> 4, li = lane & 15, li7 = lane & 7;
  int swzV = (li ^ (li >> 2)) & 3;
  int h = hh * 4 + w;

  __shared__ __align__(16) unsigned short Kl[2][2048];  // 32 rows x 64 d (4KB)
  __shared__ __align__(16) unsigned short Vl[2][2048];  // 64 rows x 32 j (4KB)

  int rk = t >> 3;
  int ck = ((t & 7) ^ (rk & 7)) * 8;
  int rv = t >> 2;
  int cv = ((t & 3) ^ ((rv ^ (rv >> 2)) & 3)) * 8;

  const unsigned short* kbase = kbuf + (size_t)b * LPAD * 64;
  const unsigned short* vbase = vt + (size_t)b * 64 * LPAD;

  bf16x8 qf[2][2];
#pragma unroll
  for (int fi = 0; fi < 2; fi++)
#pragma unroll
    for (int ks = 0; ks < 2; ks++)
      qf[fi][ks] = *reinterpret_cast<const bf16x8*>(
          q + (size_t)(b * NSEQ + i0 + fi * 16 + li) * CDIM + h * 64 + ks * 32 + G * 8);

  int jt0 = sp * 19;  // 76 tiles of 32 / 4 splits = 19 exact

  {
    int j0 = jt0 * 32;
    stage16(kbase + (size_t)(j0 + rk) * 64 + ck, &Kl[0][w * 512]);
    stage16(vbase + (size_t)rv * LPAD + j0 + cv, &Vl[0][w * 512]);
  }

  f32x4 zero = {0.f, 0.f, 0.f, 0.f};
  f32x4 OT[4][2];
#pragma unroll
  for (int fd = 0; fd < 4; fd++)
#pragma unroll
    for (int fi = 0; fi < 2; fi++) OT[fd][fi] = zero;
  float l_[2] = {0.f, 0.f};

  __syncthreads();

  for (int u = 0; u < 19; u++) {
    int jt = jt0 + u;
    int cur = u & 1, nxt = cur ^ 1;
    int j0 = jt * 32;
    if (u + 1 < 19) {
      int j1 = j0 + 32;
      stage16(kbase + (size_t)(j1 + rk) * 64 + ck, &Kl[nxt][w * 512]);
      stage16(vbase + (size_t)rv * LPAD + j1 + cv, &Vl[nxt][w * 512]);
    }
    const char* Kc = (const char*)Kl[cur];
    const char* Vc = (const char*)Vl[cur];

    f32x4 S[2][2];
#pragma unroll
    for (int fj = 0; fj < 2; fj++) { S[fj][0] = zero; S[fj][1] = zero; }
#pragma unroll
    for (int ks = 0; ks < 2; ks++) {
      bf16x8 kf[2];
#pragma unroll
      for (int fj = 0; fj < 2; fj++)
        kf[fj] = *reinterpret_cast<const bf16x8*>(
            Kc + ((((fj * 16 + li) * 8) + ((ks * 4 + G) ^ li7)) << 4));
#pragma unroll
      for (int fj = 0; fj < 2; fj++)
#pragma unroll
        for (int fi = 0; fi < 2; fi++)
          S[fj][fi] = MFMA(kf[fj], qf[fi][ks], S[fj][fi]);
    }
    if (j0 + 32 > LKV) {
#pragma unroll
      for (int fj = 0; fj < 2; fj++)
#pragma unroll
        for (int r = 0; r < 4; r++) {
          int jg = j0 + fj * 16 + G * 4 + r;
          if (jg >= LKV) { S[fj][0][r] = -1e30f; S[fj][1][r] = -1e30f; }
        }
    }
    bf16x8 pf[2];
#pragma unroll
    for (int fi = 0; fi < 2; fi++) {
      float e[2][4];
#pragma unroll
      for (int fj = 0; fj < 2; fj++)
#pragma unroll
        for (int r = 0; r < 4; r++) e[fj][r] = __builtin_exp2f(S[fj][fi][r]);
      float s0 = (e[0][0] + e[0][1]) + (e[0][2] + e[0][3]);
      float s1 = (e[1][0] + e[1][1]) + (e[1][2] + e[1][3]);
      l_[fi] += s0 + s1;
      union { unsigned int w4[4]; bf16x8 v; } u2;
#pragma unroll
      for (int m = 0; m < 4; m++) u2.w4[m] = cvtpk(e[0][m], e[1][m]);
      pf[fi] = u2.v;
    }
#pragma unroll
    for (int fd = 0; fd < 4; fd++) {
      bf16x8 uv = *reinterpret_cast<const bf16x8*>(
          Vc + (((fd * 16 + li) * 4 + (G ^ swzV)) << 4));
#pragma unroll
      for (int fi = 0; fi < 2; fi++) OT[fd][fi] = MFMA(uv, pf[fi], OT[fd][fi]);
    }
    __syncthreads();
  }

  unsigned short* pO = (sp == 0) ? pO0 : (sp == 1) ? pO1 : (sp == 2) ? pO2 : pO3;
#pragma unroll
  for (int fi = 0; fi < 2; fi++) {
    l_[fi] += __shfl_xor(l_[fi], 16);
    l_[fi] += __shfl_xor(l_[fi], 32);
    int row = b * NSEQ + i0 + fi * 16 + li;
    if (G == 0) lp[sp * LPSZ + row * 8 + h] = f2bf(l_[fi]);
#pragma unroll
    for (int fd = 0; fd < 4; fd++) {
      union { unsigned int w2[2]; uint2 u2; } pk;
      pk.w2[0] = cvtpk(OT[fd][fi][0], OT[fd][fi][1]);
      pk.w2[1] = cvtpk(OT[fd][fi][2], OT[fd][fi][3]);
      *reinterpret_cast<uint2*>(pO + (size_t)row * CDIM + h * 64 + fd * 16 + G * 4) = pk.u2;
    }
  }
}

// ---------------- merge the four KV-split partials ----------------
__global__ void k_merge(unsigned short* __restrict__ pO0,
                        const unsigned short* __restrict__ pO1,
                        const unsigned short* __restrict__ pO2,
                        const unsigned short* __restrict__ pO3,
                        const unsigned short* __restrict__ lp) {
  int c = blockIdx.x * 256 + threadIdx.x;
  size_t base = (size_t)c * 8;
  int row = (int)(base >> 9);
  int h = (int)((base >> 6) & 7);
  int li = row * 8 + h;
  float l = bf2f(lp[li]) + bf2f(lp[LPSZ + li]) + bf2f(lp[2 * LPSZ + li]) + bf2f(lp[3 * LPSZ + li]);
  float inv = 1.0f / l;
  union { uint4 u; unsigned short s[8]; } a0, a1, a2, a3, o;
  a0.u = *reinterpret_cast<const uint4*>(pO0 + base);
  a1.u = *reinterpret_cast<const uint4*>(pO1 + base);
  a2.u = *reinterpret_cast<const uint4*>(pO2 + base);
  a3.u = *reinterpret_cast<const uint4*>(pO3 + base);
  unsigned int* ow = reinterpret_cast<unsigned int*>(&o.u);
#pragma unroll
  for (int m = 0; m < 4; m++) {
    float v0 = (bf2f(a0.s[2 * m]) + bf2f(a1.s[2 * m]) + bf2f(a2.s[2 * m]) + bf2f(a3.s[2 * m])) * inv;
    float v1 = (bf2f(a0.s[2 * m + 1]) + bf2f(a1.s[2 * m + 1]) + bf2f(a2.s[2 * m + 1]) +
                bf2f(a3.s[2 * m + 1])) * inv;
    ow[m] = cvtpk(v0, v1);
  }
  *reinterpret_cast<uint4*>(pO0 + base) = o.u;
}

// ---------------- per-row LN stats of proj (coalesced) ----------------
__global__ void k_stats(const float* __restrict__ proj, float* __restrict__ musig) {
  int w = threadIdx.x >> 6, lane = threadIdx.x & 63;
  int row = blockIdx.x * 4 + w;
  const float* pr = proj + (size_t)row * CDIM;
  const float4* p4 = reinterpret_cast<const float4*>(pr + lane * 8);
  float4 a = p4[0], bq = p4[1];
  float s = a.x + a.y + a.z + a.w + bq.x + bq.y + bq.z + bq.w;
  float s2 = a.x * a.x + a.y * a.y + a.z * a.z + a.w * a.w +
             bq.x * bq.x + bq.y * bq.y + bq.z * bq.z + bq.w * bq.w;
  for (int o = 32; o; o >>= 1) { s += __shfl_xor(s, o); s2 += __shfl_xor(s2, o); }
  if (lane == 0) {
    float mu = s * (1.0f / 512.0f);
    float var = s2 * (1.0f / 512.0f) - mu * mu;
    musig[row] = mu;
    musig[4 * NSEQ + row] = rsqrtf(var + 1e-5f);
  }
}

// ---------------- final LN + residual, LDS-transposed, fully coalesced ------
__global__ void k_final2(const float* __restrict__ proj, const float* __restrict__ musig,
                         const float* __restrict__ g, const float* __restrict__ x,
                         float* __restrict__ y) {
  int i0 = blockIdx.x * 32, c0 = blockIdx.y * 64, b = blockIdx.z;
  int t = threadIdx.x;
  __shared__ float lds[32][65];
  {
    int il = t >> 3, cB = (t & 7) * 8;
    const float4* src = reinterpret_cast<const float4*>(
        proj + (size_t)(b * NSEQ + i0 + il) * CDIM + c0 + cB);
    float4 v0 = src[0], v1 = src[1];
    *reinterpret_cast<float4*>(&lds[il][cB]) = v0;
    *reinterpret_cast<float4*>(&lds[il][cB + 4]) = v1;
  }
  __syncthreads();
  int ii = t & 31, cg = t >> 5;
  float mu = musig[b * NSEQ + i0 + ii];
  float rs = musig[4 * NSEQ + b * NSEQ + i0 + ii];
  const float* xb = x + (size_t)b * CDIM * NSEQ;
  float* yb = y + (size_t)b * CDIM * NSEQ;
#pragma unroll
  for (int cc = 0; cc < 8; cc++) {
    int cl = cg * 8 + cc;
    int c = c0 + cl;
    float v = lds[ii][cl];
    yb[(size_t)c * NSEQ + i0 + ii] = xb[(size_t)c * NSEQ + i0 + ii] + (v - mu) * rs * g[c];
  }
}

extern "C" void kernel_launch(void* const* d_in, const int* in_sizes, int n_in,
                              void* d_out, int out_size, void* d_ws, size_t ws_size,
                              hipStream_t stream) {
  const float* x       = (const float*)d_in[0];
  const float* context = (const float*)d_in[1];
  const float* ngamma  = (const float*)d_in[2];
  const float* null_kv = (const float*)d_in[3];
  const float* Wq      = (const float*)d_in[4];
  const float* Wkv     = (const float*)d_in[5];
  const float* clng    = (const float*)d_in[6];
  const float* clnb    = (const float*)d_in[7];
  const float* Wctx    = (const float*)d_in[8];
  const float* bctx    = (const float*)d_in[9];
  const float* Wout    = (const float*)d_in[10];
  const float* olng    = (const float*)d_in[11];
  float* y = (float*)d_out;
  char* ws = (char*)d_ws;

  unsigned short* xn    = (unsigned short*)(ws);              // 9437184 B (pO1 during attn)
  unsigned short* qb    = (unsigned short*)(ws + 9437184);    // 9437184 B
  float* proj           = (float*)(ws);                       // aliases xn+qb (dead by then)
  unsigned short* aoutb = (unsigned short*)(ws + 18874368);   // 9437184 B (pO0 -> merged)
  float* musig          = (float*)(ws + 18874368);            // aliases aoutb (dead after gemm1)
  unsigned short* kb    = (unsigned short*)(ws + 28311552);   // 1245184 B
  unsigned short* vtb   = (unsigned short*)(ws + 29556736);   // 1245184 B
  unsigned short* WqT   = (unsigned short*)(ws + 30801920);   // 524288 B
  unsigned short* WkvT  = (unsigned short*)(ws + 31326208);   // 131072 B
  unsigned short* WctxT = (unsigned short*)(ws + 31457280);   // 196608 B
  unsigned short* WoutT = (unsigned short*)(ws + 31653888);   // 524288 B
  // bf16 l-partials: 4 x 73728 x 2B = 589824 B, overlay WqT+WkvT (dead after gemm0)
  unsigned short* lpart = (unsigned short*)(ws + 30801920);
  // partials 2,3 live in d_out (18874368 B); k_final2 fully rewrites y after.
  unsigned short* pO2   = (unsigned short*)d_out;
  unsigned short* pO3   = (unsigned short*)d_out + 4718592;

  k_prep<<<dim3(672), dim3(256), 0, stream>>>(Wq, Wkv, Wctx, Wout, WqT, WkvT, WctxT, WoutT);
  k_ln1<<<dim3(72, 4), dim3(256), 0, stream>>>(x, ngamma, xn);
  k_ctx<<<dim3(128, 4), dim3(128), 0, stream>>>(context, clng, clnb, WctxT, bctx, null_kv, kb, vtb);
  k_gemm<0><<<dim3(72, 10), dim3(256), 0, stream>>>(xn, WqT, WkvT, qb, kb, vtb, nullptr);
  k_attn<<<dim3(288, 2, 4), dim3(256), 0, stream>>>(qb, kb, vtb, aoutb, xn, pO2, pO3, lpart);
  k_merge<<<dim3(2304), dim3(256), 0, stream>>>(aoutb, xn, pO2, pO3, lpart);
  k_gemm<1><<<dim3(72, 8), dim3(256), 0, stream>>>(aoutb, WoutT, nullptr, nullptr, nullptr, nullptr, proj);
  k_stats<<<dim3(2304), dim3(256), 0, stream>>>(proj, musig);
  k_final2<<<dim3(72, 8, 4), dim3(256), 0, stream>>>(proj, musig, olng, x, y);
}

// Round 16
// 168.459 us; speedup vs baseline: 3.2914x; 1.0179x over previous
//
#include <hip/hip_runtime.h>

typedef __attribute__((ext_vector_type(8))) short bf16x8;
typedef __attribute__((ext_vector_type(4))) float f32x4;

#define LPAD 2432
#define LKV  2382
#define NSEQ 2304
#define CDIM 512
#define LPSZ (4 * NSEQ * 8)  // l-partial entries per split (rows*heads)

__device__ __forceinline__ unsigned short f2bf(float f) {
  unsigned int u = __builtin_bit_cast(unsigned int, f);
  u += 0x7fffu + ((u >> 16) & 1u);
  return (unsigned short)(u >> 16);
}
__device__ __forceinline__ float bf2f(unsigned short s) {
  unsigned int u = ((unsigned int)s) << 16;
  return __builtin_bit_cast(float, u);
}
__device__ __forceinline__ f32x4 MFMA(bf16x8 a, bf16x8 b, f32x4 c) {
  return __builtin_amdgcn_mfma_f32_16x16x32_bf16(a, b, c, 0, 0, 0);
}
__device__ __forceinline__ void stage16(const unsigned short* g, unsigned short* l) {
  __builtin_amdgcn_global_load_lds((const __attribute__((address_space(1))) void*)g,
                                   (__attribute__((address_space(3))) void*)l, 16, 0, 0);
}
__device__ __forceinline__ unsigned int cvtpk(float a, float b) {
  unsigned int r;
  asm("v_cvt_pk_bf16_f32 %0, %1, %2" : "=v"(r) : "v"(a), "v"(b));
  return r;
}
// interleaved V^T column position within each 32-chunk
__device__ __forceinline__ int Fj(int j) {
  return (j & ~31) | ((j & 15) << 1) | ((j >> 4) & 1);
}

// ---------------- weight transpose + bf16 convert (LDS tiled, coalesced) ----
__device__ __forceinline__ void tr_tile(const float* __restrict__ in,
                                        unsigned short* __restrict__ out,
                                        int K, int N, int tk, int tn, int t) {
  __shared__ float T[32][33];
  int r = t >> 5, c = t & 31;
#pragma unroll
  for (int p = 0; p < 4; p++) {
    int rr = r + p * 8;
    T[rr][c] = in[(size_t)(tk * 32 + rr) * N + tn * 32 + c];
  }
  __syncthreads();
#pragma unroll
  for (int p = 0; p < 4; p++) {
    int rr = r + p * 8;
    out[(size_t)(tn * 32 + rr) * K + tk * 32 + c] = f2bf(T[c][rr]);
  }
}

__global__ void k_prep(const float* __restrict__ Wq, const float* __restrict__ Wkv,
                       const float* __restrict__ Wctx, const float* __restrict__ Wout,
                       unsigned short* __restrict__ WqT, unsigned short* __restrict__ WkvT,
                       unsigned short* __restrict__ WctxT, unsigned short* __restrict__ WoutT) {
  int bid = blockIdx.x, t = threadIdx.x;
  if (bid < 256) {
    tr_tile(Wq, WqT, 512, 512, bid >> 4, bid & 15, t);
  } else if (bid < 320) {
    int q = bid - 256;
    tr_tile(Wkv, WkvT, 512, 128, q >> 2, q & 3, t);
  } else if (bid < 416) {
    int q = bid - 320;
    tr_tile(Wctx, WctxT, 768, 128, q >> 2, q & 3, t);
  } else {
    int q = bid - 416;
    tr_tile(Wout, WoutT, 512, 512, q >> 4, q & 15, t);
  }
}

// ---------------- LN over C of x (B,C,N) -> xn bf16 (B*N, C) ----------------
__global__ void k_ln1(const float* __restrict__ x, const float* __restrict__ g,
                      unsigned short* __restrict__ xn) {
  int b = blockIdx.y;
  int i0 = blockIdx.x * 32;
  int t = threadIdx.x;
  int ii = t & 31, ci = t >> 5;
  const float* xb = x + (size_t)b * CDIM * NSEQ;
  float s = 0.f, s2 = 0.f;
  for (int c = ci; c < CDIM; c += 8) {
    float v = xb[(size_t)c * NSEQ + i0 + ii];
    s += v; s2 += v * v;
  }
  __shared__ float ls[8][32], ls2[8][32];
  __shared__ float lmu[32], lrs[32];
  __shared__ float Lt[32][65];
  ls[ci][ii] = s; ls2[ci][ii] = s2;
  __syncthreads();
  if (t < 32) {
    float a = 0.f, a2 = 0.f;
    for (int q = 0; q < 8; q++) { a += ls[q][t]; a2 += ls2[q][t]; }
    float mu = a * (1.0f / 512.0f);
    float var = a2 * (1.0f / 512.0f) - mu * mu;
    lmu[t] = mu; lrs[t] = rsqrtf(var + 1e-5f);
  }
  __syncthreads();
  float mu = lmu[ii], rs = lrs[ii];
  int rr = t >> 3, cl0 = (t & 7) * 8;
  for (int cb = 0; cb < 8; cb++) {
#pragma unroll
    for (int e = 0; e < 8; e++) {
      int cl = ci + 8 * e;
      int c = cb * 64 + cl;
      float v = xb[(size_t)c * NSEQ + i0 + ii];
      Lt[ii][cl] = (v - mu) * rs * g[c];
    }
    __syncthreads();
    union { unsigned int w4[4]; uint4 u; } pk;
#pragma unroll
    for (int m = 0; m < 4; m++)
      pk.w4[m] = cvtpk(Lt[rr][cl0 + 2 * m], Lt[rr][cl0 + 2 * m + 1]);
    *reinterpret_cast<uint4*>(xn + (size_t)(b * NSEQ + i0 + rr) * CDIM + cb * 64 + cl0) = pk.u;
    __syncthreads();
  }
}

// ---------------- context LN + projection; null row + zero pads ----------
__global__ void k_ctx(const float* __restrict__ ctx, const float* __restrict__ g,
                      const float* __restrict__ be, const unsigned short* __restrict__ WctxT,
                      const float* __restrict__ bctx, const float* __restrict__ null_kv,
                      unsigned short* __restrict__ kb, unsigned short* __restrict__ vt) {
  int b = blockIdx.y, j = blockIdx.x;
  int t = threadIdx.x;
  if (j == 77) {
    if (t < 64) kb[((size_t)b * LPAD + 77) * 64 + t] = f2bf(null_kv[t]);
    else vt[((size_t)b * 64 + (t - 64)) * LPAD + Fj(77)] = f2bf(null_kv[64 + (t - 64)]);
    return;
  }
  if (j > 77) {
    int jj = LKV + (j - 78);
    if (t < 64) kb[((size_t)b * LPAD + jj) * 64 + t] = 0;
    else vt[((size_t)b * 64 + (t - 64)) * LPAD + Fj(jj)] = 0;
    return;
  }
  __shared__ float row[768];
  __shared__ float red[4];
  const float* src = ctx + (size_t)(b * 77 + j) * 768;
  float s = 0.f, s2 = 0.f;
  for (int k = t; k < 768; k += 128) {
    float v = src[k];
    row[k] = v; s += v; s2 += v * v;
  }
  for (int o = 32; o; o >>= 1) { s += __shfl_xor(s, o); s2 += __shfl_xor(s2, o); }
  if ((t & 63) == 0) { red[(t >> 6) * 2] = s; red[(t >> 6) * 2 + 1] = s2; }
  __syncthreads();
  float S = red[0] + red[2], S2 = red[1] + red[3];
  float mu = S * (1.0f / 768.0f);
  float rs = rsqrtf(S2 * (1.0f / 768.0f) - mu * mu + 1e-5f);
  __syncthreads();
  for (int k = t; k < 768; k += 128) row[k] = (row[k] - mu) * rs * g[k] + be[k];
  __syncthreads();
  const uint4* w4 = reinterpret_cast<const uint4*>(WctxT + (size_t)t * 768);
  float acc = 0.f;
  for (int k8 = 0; k8 < 96; k8++) {
    union { uint4 u; unsigned short s[8]; } wv;
    wv.u = w4[k8];
#pragma unroll
    for (int e = 0; e < 8; e++) acc += row[k8 * 8 + e] * bf2f(wv.s[e]);
  }
  acc += bctx[t];
  if (t < 64) kb[((size_t)b * LPAD + j) * 64 + t] = f2bf(acc);
  else vt[((size_t)b * 64 + (t - 64)) * LPAD + Fj(j)] = f2bf(acc);
}

// ---------------- MFMA GEMM: BM=128 BN=64 BK=64, global_load_lds + dbuf -----
// MODE 1 writes proj as bf16 (downstream LN is scale-tolerant) — ONLY change
// from the R14 passing kernel.
template <int MODE>
__global__ __launch_bounds__(256, 1) void k_gemm(
    const unsigned short* __restrict__ A, const unsigned short* __restrict__ BT0,
    const unsigned short* __restrict__ BT1, unsigned short* __restrict__ out_q,
    unsigned short* __restrict__ out_k, unsigned short* __restrict__ out_vt,
    unsigned short* __restrict__ out_proj) {
  int m0 = blockIdx.x * 128, n0 = blockIdx.y * 64;
  int t = threadIdx.x;
  int lane = t & 63, w = t >> 6;
  int wm = w >> 1, wn = w & 1;
  int G = lane >> 4, li = lane & 15, li7 = lane & 7;
  __shared__ __align__(16) unsigned short Al[2][8192];  // 128 x 64
  __shared__ __align__(16) unsigned short Bl[2][4096];  // 64 x 64
  const unsigned short* BT = (MODE == 0 && n0 >= 512) ? BT1 : BT0;
  int bn0 = (MODE == 0 && n0 >= 512) ? n0 - 512 : n0;

  f32x4 zero = {0.f, 0.f, 0.f, 0.f};
  f32x4 acc[4][2];
#pragma unroll
  for (int a = 0; a < 4; a++)
#pragma unroll
    for (int c = 0; c < 2; c++) acc[a][c] = zero;

#define STAGE_AB(buf, k0)                                                              \
  {                                                                                    \
    _Pragma("unroll") for (int p = 0; p < 4; p++) {                                    \
      int gA = p * 256 + t;                                                            \
      int ra = gA >> 3;                                                                \
      int ca = ((gA & 7) ^ (ra & 7)) * 8;                                              \
      stage16(A + (size_t)(m0 + ra) * 512 + (k0) + ca, &Al[buf][(p * 256 + w * 64) * 8]); \
    }                                                                                  \
    _Pragma("unroll") for (int p = 0; p < 2; p++) {                                    \
      int gB = p * 256 + t;                                                            \
      int rb = gB >> 3;                                                                \
      int cb = ((gB & 7) ^ (rb & 7)) * 8;                                              \
      stage16(BT + (size_t)(bn0 + rb) * 512 + (k0) + cb, &Bl[buf][(p * 256 + w * 64) * 8]); \
    }                                                                                  \
  }

  STAGE_AB(0, 0)
  __syncthreads();

  for (int u = 0; u < 8; u++) {
    int cur = u & 1, nxt = cur ^ 1;
    if (u < 7) STAGE_AB(nxt, (u + 1) * 64)
    const char* Ac = (const char*)Al[cur];
    const char* Bc = (const char*)Bl[cur];
#pragma unroll
    for (int ks = 0; ks < 2; ks++) {
      bf16x8 af[4], bfr[2];
#pragma unroll
      for (int f = 0; f < 4; f++)
        af[f] = *reinterpret_cast<const bf16x8*>(
            Ac + ((((wm * 64 + f * 16 + li) * 8) + ((ks * 4 + G) ^ li7)) << 4));
#pragma unroll
      for (int f = 0; f < 2; f++)
        bfr[f] = *reinterpret_cast<const bf16x8*>(
            Bc + ((((wn * 32 + f * 16 + li) * 8) + ((ks * 4 + G) ^ li7)) << 4));
#pragma unroll
      for (int fm = 0; fm < 4; fm++)
#pragma unroll
        for (int fn = 0; fn < 2; fn++)
          acc[fm][fn] = MFMA(af[fm], bfr[fn], acc[fm][fn]);
    }
    __syncthreads();
  }
#undef STAGE_AB

#pragma unroll
  for (int fm = 0; fm < 4; fm++)
#pragma unroll
    for (int fn = 0; fn < 2; fn++)
#pragma unroll
      for (int r = 0; r < 4; r++) {
        int row = m0 + wm * 64 + fm * 16 + G * 4 + r;
        int col = n0 + wn * 32 + fn * 16 + li;
        float v = acc[fm][fn][r];
        if (MODE == 0) {
          int b = row / NSEQ, i = row - b * NSEQ;
          // q pre-scaled by 1/sqrt(dh) * log2(e): softmax runs in exp2 domain
          if (col < 512) out_q[(size_t)row * 512 + col] = f2bf(v * 0.18033688011112042f);
          else if (col < 576) out_k[((size_t)b * LPAD + 78 + i) * 64 + (col - 512)] = f2bf(v);
          else out_vt[((size_t)b * 64 + (col - 576)) * LPAD + Fj(78 + i)] = f2bf(v);
        } else {
          out_proj[(size_t)row * 512 + col] = f2bf(v);
        }
      }
}

// ---------------- flash attention: 4-way KV split, KVBLK=32, 16KB LDS -------
// (byte-identical to the R14 passing kernel)
__global__ __launch_bounds__(256, 4) void k_attn(
    const unsigned short* __restrict__ q, const unsigned short* __restrict__ kbuf,
    const unsigned short* __restrict__ vt, unsigned short* __restrict__ pO0,
    unsigned short* __restrict__ pO1, unsigned short* __restrict__ pO2,
    unsigned short* __restrict__ pO3, unsigned short* __restrict__ lp) {
  int bx = blockIdx.x;
  int it = bx >> 2, sp = bx & 3;
  int hh = blockIdx.y, b = blockIdx.z;
  int i0 = it * 32;
  int t = threadIdx.x;
  int w = t >> 6, lane = t & 63;
  int G = lane >> 4, li = lane & 15, li7 = lane & 7;
  int swzV = (li ^ (li >> 2)) & 3;
  int h = hh * 4 + w;

  __shared__ __align__(16) unsigned short Kl[2][2048];  // 32 rows x 64 d (4KB)
  __shared__ __align__(16) unsigned short Vl[2][2048];  // 64 rows x 32 j (4KB)

  int rk = t >> 3;
  int ck = ((t & 7) ^ (rk & 7)) * 8;
  int rv = t >> 2;
  int cv = ((t & 3) ^ ((rv ^ (rv >> 2)) & 3)) * 8;

  const unsigned short* kbase = kbuf + (size_t)b * LPAD * 64;
  const unsigned short* vbase = vt + (size_t)b * 64 * LPAD;

  bf16x8 qf[2][2];
#pragma unroll
  for (int fi = 0; fi < 2; fi++)
#pragma unroll
    for (int ks = 0; ks < 2; ks++)
      qf[fi][ks] = *reinterpret_cast<const bf16x8*>(
          q + (size_t)(b * NSEQ + i0 + fi * 16 + li) * CDIM + h * 64 + ks * 32 + G * 8);

  int jt0 = sp * 19;  // 76 tiles of 32 / 4 splits = 19 exact

  {
    int j0 = jt0 * 32;
    stage16(kbase + (size_t)(j0 + rk) * 64 + ck, &Kl[0][w * 512]);
    stage16(vbase + (size_t)rv * LPAD + j0 + cv, &Vl[0][w * 512]);
  }

  f32x4 zero = {0.f, 0.f, 0.f, 0.f};
  f32x4 OT[4][2];
#pragma unroll
  for (int fd = 0; fd < 4; fd++)
#pragma unroll
    for (int fi = 0; fi < 2; fi++) OT[fd][fi] = zero;
  float l_[2] = {0.f, 0.f};

  __syncthreads();

  for (int u = 0; u < 19; u++) {
    int jt = jt0 + u;
    int cur = u & 1, nxt = cur ^ 1;
    int j0 = jt * 32;
    if (u + 1 < 19) {
      int j1 = j0 + 32;
      stage16(kbase + (size_t)(j1 + rk) * 64 + ck, &Kl[nxt][w * 512]);
      stage16(vbase + (size_t)rv * LPAD + j1 + cv, &Vl[nxt][w * 512]);
    }
    const char* Kc = (const char*)Kl[cur];
    const char* Vc = (const char*)Vl[cur];

    f32x4 S[2][2];
#pragma unroll
    for (int fj = 0; fj < 2; fj++) { S[fj][0] = zero; S[fj][1] = zero; }
#pragma unroll
    for (int ks = 0; ks < 2; ks++) {
      bf16x8 kf[2];
#pragma unroll
      for (int fj = 0; fj < 2; fj++)
        kf[fj] = *reinterpret_cast<const bf16x8*>(
            Kc + ((((fj * 16 + li) * 8) + ((ks * 4 + G) ^ li7)) << 4));
#pragma unroll
      for (int fj = 0; fj < 2; fj++)
#pragma unroll
        for (int fi = 0; fi < 2; fi++)
          S[fj][fi] = MFMA(kf[fj], qf[fi][ks], S[fj][fi]);
    }
    if (j0 + 32 > LKV) {
#pragma unroll
      for (int fj = 0; fj < 2; fj++)
#pragma unroll
        for (int r = 0; r < 4; r++) {
          int jg = j0 + fj * 16 + G * 4 + r;
          if (jg >= LKV) { S[fj][0][r] = -1e30f; S[fj][1][r] = -1e30f; }
        }
    }
    bf16x8 pf[2];
#pragma unroll
    for (int fi = 0; fi < 2; fi++) {
      float e[2][4];
#pragma unroll
      for (int fj = 0; fj < 2; fj++)
#pragma unroll
        for (int r = 0; r < 4; r++) e[fj][r] = __builtin_exp2f(S[fj][fi][r]);
      float s0 = (e[0][0] + e[0][1]) + (e[0][2] + e[0][3]);
      float s1 = (e[1][0] + e[1][1]) + (e[1][2] + e[1][3]);
      l_[fi] += s0 + s1;
      union { unsigned int w4[4]; bf16x8 v; } u2;
#pragma unroll
      for (int m = 0; m < 4; m++) u2.w4[m] = cvtpk(e[0][m], e[1][m]);
      pf[fi] = u2.v;
    }
#pragma unroll
    for (int fd = 0; fd < 4; fd++) {
      bf16x8 uv = *reinterpret_cast<const bf16x8*>(
          Vc + (((fd * 16 + li) * 4 + (G ^ swzV)) << 4));
#pragma unroll
      for (int fi = 0; fi < 2; fi++) OT[fd][fi] = MFMA(uv, pf[fi], OT[fd][fi]);
    }
    __syncthreads();
  }

  unsigned short* pO = (sp == 0) ? pO0 : (sp == 1) ? pO1 : (sp == 2) ? pO2 : pO3;
#pragma unroll
  for (int fi = 0; fi < 2; fi++) {
    l_[fi] += __shfl_xor(l_[fi], 16);
    l_[fi] += __shfl_xor(l_[fi], 32);
    int row = b * NSEQ + i0 + fi * 16 + li;
    if (G == 0) lp[sp * LPSZ + row * 8 + h] = f2bf(l_[fi]);
#pragma unroll
    for (int fd = 0; fd < 4; fd++) {
      union { unsigned int w2[2]; uint2 u2; } pk;
      pk.w2[0] = cvtpk(OT[fd][fi][0], OT[fd][fi][1]);
      pk.w2[1] = cvtpk(OT[fd][fi][2], OT[fd][fi][3]);
      *reinterpret_cast<uint2*>(pO + (size_t)row * CDIM + h * 64 + fd * 16 + G * 4) = pk.u2;
    }
  }
}

// ---------------- merge the four KV-split partials ----------------
__global__ void k_merge(unsigned short* __restrict__ pO0,
                        const unsigned short* __restrict__ pO1,
                        const unsigned short* __restrict__ pO2,
                        const unsigned short* __restrict__ pO3,
                        const unsigned short* __restrict__ lp) {
  int c = blockIdx.x * 256 + threadIdx.x;
  size_t base = (size_t)c * 8;
  int row = (int)(base >> 9);
  int h = (int)((base >> 6) & 7);
  int li = row * 8 + h;
  float l = bf2f(lp[li]) + bf2f(lp[LPSZ + li]) + bf2f(lp[2 * LPSZ + li]) + bf2f(lp[3 * LPSZ + li]);
  float inv = 1.0f / l;
  union { uint4 u; unsigned short s[8]; } a0, a1, a2, a3, o;
  a0.u = *reinterpret_cast<const uint4*>(pO0 + base);
  a1.u = *reinterpret_cast<const uint4*>(pO1 + base);
  a2.u = *reinterpret_cast<const uint4*>(pO2 + base);
  a3.u = *reinterpret_cast<const uint4*>(pO3 + base);
  unsigned int* ow = reinterpret_cast<unsigned int*>(&o.u);
#pragma unroll
  for (int m = 0; m < 4; m++) {
    float v0 = (bf2f(a0.s[2 * m]) + bf2f(a1.s[2 * m]) + bf2f(a2.s[2 * m]) + bf2f(a3.s[2 * m])) * inv;
    float v1 = (bf2f(a0.s[2 * m + 1]) + bf2f(a1.s[2 * m + 1]) + bf2f(a2.s[2 * m + 1]) +
                bf2f(a3.s[2 * m + 1])) * inv;
    ow[m] = cvtpk(v0, v1);
  }
  *reinterpret_cast<uint4*>(pO0 + base) = o.u;
}

// ---------------- per-row LN stats of proj (bf16, coalesced) ----------------
__global__ void k_stats(const unsigned short* __restrict__ proj, float* __restrict__ musig) {
  int w = threadIdx.x >> 6, lane = threadIdx.x & 63;
  int row = blockIdx.x * 4 + w;
  union { uint4 u; unsigned short s[8]; } a;
  a.u = *reinterpret_cast<const uint4*>(proj + (size_t)row * CDIM + lane * 8);
  float s = 0.f, s2 = 0.f;
#pragma unroll
  for (int m = 0; m < 8; m++) {
    float v = bf2f(a.s[m]);
    s += v; s2 += v * v;
  }
  for (int o = 32; o; o >>= 1) { s += __shfl_xor(s, o); s2 += __shfl_xor(s2, o); }
  if (lane == 0) {
    float mu = s * (1.0f / 512.0f);
    float var = s2 * (1.0f / 512.0f) - mu * mu;
    musig[row] = mu;
    musig[4 * NSEQ + row] = rsqrtf(var + 1e-5f);
  }
}

// ---------------- final LN + residual, LDS-transposed, fully coalesced ------
__global__ void k_final2(const unsigned short* __restrict__ proj, const float* __restrict__ musig,
                         const float* __restrict__ g, const float* __restrict__ x,
                         float* __restrict__ y) {
  int i0 = blockIdx.x * 32, c0 = blockIdx.y * 64, b = blockIdx.z;
  int t = threadIdx.x;
  __shared__ float lds[32][65];
  {
    int il = t >> 3, cB = (t & 7) * 8;
    union { uint4 u; unsigned short s[8]; } a;
    a.u = *reinterpret_cast<const uint4*>(proj + (size_t)(b * NSEQ + i0 + il) * CDIM + c0 + cB);
#pragma unroll
    for (int m = 0; m < 8; m++) lds[il][cB + m] = bf2f(a.s[m]);
  }
  __syncthreads();
  int ii = t & 31, cg = t >> 5;
  float mu = musig[b * NSEQ + i0 + ii];
  float rs = musig[4 * NSEQ + b * NSEQ + i0 + ii];
  const float* xb = x + (size_t)b * CDIM * NSEQ;
  float* yb = y + (size_t)b * CDIM * NSEQ;
#pragma unroll
  for (int cc = 0; cc < 8; cc++) {
    int cl = cg * 8 + cc;
    int c = c0 + cl;
    float v = lds[ii][cl];
    yb[(size_t)c * NSEQ + i0 + ii] = xb[(size_t)c * NSEQ + i0 + ii] + (v - mu) * rs * g[c];
  }
}

extern "C" void kernel_launch(void* const* d_in, const int* in_sizes, int n_in,
                              void* d_out, int out_size, void* d_ws, size_t ws_size,
                              hipStream_t stream) {
  const float* x       = (const float*)d_in[0];
  const float* context = (const float*)d_in[1];
  const float* ngamma  = (const float*)d_in[2];
  const float* null_kv = (const float*)d_in[3];
  const float* Wq      = (const float*)d_in[4];
  const float* Wkv     = (const float*)d_in[5];
  const float* clng    = (const float*)d_in[6];
  const float* clnb    = (const float*)d_in[7];
  const float* Wctx    = (const float*)d_in[8];
  const float* bctx    = (const float*)d_in[9];
  const float* Wout    = (const float*)d_in[10];
  const float* olng    = (const float*)d_in[11];
  float* y = (float*)d_out;
  char* ws = (char*)d_ws;

  unsigned short* xn    = (unsigned short*)(ws);              // 9437184 B (pO1 during attn)
  unsigned short* qb    = (unsigned short*)(ws + 9437184);    // 9437184 B
  unsigned short* proj  = (unsigned short*)(ws);              // bf16, aliases xn (dead by then)
  unsigned short* aoutb = (unsigned short*)(ws + 18874368);   // 9437184 B (pO0 -> merged)
  float* musig          = (float*)(ws + 18874368);            // aliases aoutb (dead after gemm1)
  unsigned short* kb    = (unsigned short*)(ws + 28311552);   // 1245184 B
  unsigned short* vtb   = (unsigned short*)(ws + 29556736);   // 1245184 B
  unsigned short* WqT   = (unsigned short*)(ws + 30801920);   // 524288 B
  unsigned short* WkvT  = (unsigned short*)(ws + 31326208);   // 131072 B
  unsigned short* WctxT = (unsigned short*)(ws + 31457280);   // 196608 B
  unsigned short* WoutT = (unsigned short*)(ws + 31653888);   // 524288 B
  // bf16 l-partials: 4 x 73728 x 2B = 589824 B, overlay WqT+WkvT (dead after gemm0)
  unsigned short* lpart = (unsigned short*)(ws + 30801920);
  // partials 2,3 live in d_out (18874368 B); k_final2 fully rewrites y after.
  unsigned short* pO2   = (unsigned short*)d_out;
  unsigned short* pO3   = (unsigned short*)d_out + 4718592;

  k_prep<<<dim3(672), dim3(256), 0, stream>>>(Wq, Wkv, Wctx, Wout, WqT, WkvT, WctxT, WoutT);
  k_ln1<<<dim3(72, 4), dim3(256), 0, stream>>>(x, ngamma, xn);
  k_ctx<<<dim3(128, 4), dim3(128), 0, stream>>>(context, clng, clnb, WctxT, bctx, null_kv, kb, vtb);
  k_gemm<0><<<dim3(72, 10), dim3(256), 0, stream>>>(xn, WqT, WkvT, qb, kb, vtb, nullptr);
  k_attn<<<dim3(288, 2, 4), dim3(256), 0, stream>>>(qb, kb, vtb, aoutb, xn, pO2, pO3, lpart);
  k_merge<<<dim3(2304), dim3(256), 0, stream>>>(aoutb, xn, pO2, pO3, lpart);
  k_gemm<1><<<dim3(72, 8), dim3(256), 0, stream>>>(aoutb, WoutT, nullptr, nullptr, nullptr, nullptr, proj);
  k_stats<<<dim3(2304), dim3(256), 0, stream>>>(proj, musig);
  k_final2<<<dim3(72, 8, 4), dim3(256), 0, stream>>>(proj, musig, olng, x, y);
}

// Round 17
// 167.863 us; speedup vs baseline: 3.3031x; 1.0035x over previous
//
#include <hip/hip_runtime.h>

typedef __attribute__((ext_vector_type(8))) short bf16x8;
typedef __attribute__((ext_vector_type(4))) float f32x4;

#define LPAD 2432
#define LKV  2382
#define NSEQ 2304
#define CDIM 512
#define LPSZ (4 * NSEQ * 8)  // l-partial entries per split (rows*heads)

__device__ __forceinline__ unsigned short f2bf(float f) {
  unsigned int u = __builtin_bit_cast(unsigned int, f);
  u += 0x7fffu + ((u >> 16) & 1u);
  return (unsigned short)(u >> 16);
}
__device__ __forceinline__ float bf2f(unsigned short s) {
  unsigned int u = ((unsigned int)s) << 16;
  return __builtin_bit_cast(float, u);
}
__device__ __forceinline__ f32x4 MFMA(bf16x8 a, bf16x8 b, f32x4 c) {
  return __builtin_amdgcn_mfma_f32_16x16x32_bf16(a, b, c, 0, 0, 0);
}
__device__ __forceinline__ void stage16(const unsigned short* g, unsigned short* l) {
  __builtin_amdgcn_global_load_lds((const __attribute__((address_space(1))) void*)g,
                                   (__attribute__((address_space(3))) void*)l, 16, 0, 0);
}
__device__ __forceinline__ unsigned int cvtpk(float a, float b) {
  unsigned int r;
  asm("v_cvt_pk_bf16_f32 %0, %1, %2" : "=v"(r) : "v"(a), "v"(b));
  return r;
}
// interleaved V^T column position within each 32-chunk
__device__ __forceinline__ int Fj(int j) {
  return (j & ~31) | ((j & 15) << 1) | ((j >> 4) & 1);
}

// ---------------- weight transpose + bf16 convert (LDS tiled, coalesced) ----
__device__ __forceinline__ void tr_tile(const float* __restrict__ in,
                                        unsigned short* __restrict__ out,
                                        int K, int N, int tk, int tn, int t) {
  __shared__ float T[32][33];
  int r = t >> 5, c = t & 31;
#pragma unroll
  for (int p = 0; p < 4; p++) {
    int rr = r + p * 8;
    T[rr][c] = in[(size_t)(tk * 32 + rr) * N + tn * 32 + c];
  }
  __syncthreads();
#pragma unroll
  for (int p = 0; p < 4; p++) {
    int rr = r + p * 8;
    out[(size_t)(tn * 32 + rr) * K + tk * 32 + c] = f2bf(T[c][rr]);
  }
}

__global__ void k_prep(const float* __restrict__ Wq, const float* __restrict__ Wkv,
                       const float* __restrict__ Wctx, const float* __restrict__ Wout,
                       unsigned short* __restrict__ WqT, unsigned short* __restrict__ WkvT,
                       unsigned short* __restrict__ WctxT, unsigned short* __restrict__ WoutT) {
  int bid = blockIdx.x, t = threadIdx.x;
  if (bid < 256) {
    tr_tile(Wq, WqT, 512, 512, bid >> 4, bid & 15, t);
  } else if (bid < 320) {
    int q = bid - 256;
    tr_tile(Wkv, WkvT, 512, 128, q >> 2, q & 3, t);
  } else if (bid < 416) {
    int q = bid - 320;
    tr_tile(Wctx, WctxT, 768, 128, q >> 2, q & 3, t);
  } else {
    int q = bid - 416;
    tr_tile(Wout, WoutT, 512, 512, q >> 4, q & 15, t);
  }
}

// ---------------- LN over C of x (B,C,N) -> xn bf16 (B*N, C) ----------------
// Single global read: phase 1 computes stats AND stashes x as bf16 in LDS
// (Xs[32][514]: bank = 257*ii + c/2 -> conflict-free). Phase 2 reads the
// stash directly per writer thread (no Lt ping-pong, one barrier total).
__global__ void k_ln1(const float* __restrict__ x, const float* __restrict__ g,
                      unsigned short* __restrict__ xn) {
  int b = blockIdx.y;
  int i0 = blockIdx.x * 32;
  int t = threadIdx.x;
  int ii = t & 31, ci = t >> 5;
  const float* xb = x + (size_t)b * CDIM * NSEQ;
  __shared__ unsigned short Xs[32][514];
  __shared__ float ls[8][32], ls2[8][32];
  __shared__ float lmu[32], lrs[32];
  float s = 0.f, s2 = 0.f;
  for (int c = ci; c < CDIM; c += 8) {
    float v = xb[(size_t)c * NSEQ + i0 + ii];
    Xs[ii][c] = f2bf(v);
    s += v; s2 += v * v;
  }
  ls[ci][ii] = s; ls2[ci][ii] = s2;
  __syncthreads();
  if (t < 32) {
    float a = 0.f, a2 = 0.f;
    for (int q = 0; q < 8; q++) { a += ls[q][t]; a2 += ls2[q][t]; }
    float mu = a * (1.0f / 512.0f);
    float var = a2 * (1.0f / 512.0f) - mu * mu;
    lmu[t] = mu; lrs[t] = rsqrtf(var + 1e-5f);
  }
  __syncthreads();
  int rr = t >> 3, cl0 = (t & 7) * 8;
  float mu = lmu[rr], rs = lrs[rr];
  unsigned short* xrow = xn + (size_t)(b * NSEQ + i0 + rr) * CDIM;
#pragma unroll
  for (int cb = 0; cb < 8; cb++) {
    int c0 = cb * 64 + cl0;
    union { unsigned int w4[4]; uint4 u; } pk;
#pragma unroll
    for (int m = 0; m < 4; m++) {
      float v0 = (bf2f(Xs[rr][c0 + 2 * m]) - mu) * rs * g[c0 + 2 * m];
      float v1 = (bf2f(Xs[rr][c0 + 2 * m + 1]) - mu) * rs * g[c0 + 2 * m + 1];
      pk.w4[m] = cvtpk(v0, v1);
    }
    *reinterpret_cast<uint4*>(xrow + c0) = pk.u;
  }
}

// ---------------- context LN + projection; null row + zero pads ----------
__global__ void k_ctx(const float* __restrict__ ctx, const float* __restrict__ g,
                      const float* __restrict__ be, const unsigned short* __restrict__ WctxT,
                      const float* __restrict__ bctx, const float* __restrict__ null_kv,
                      unsigned short* __restrict__ kb, unsigned short* __restrict__ vt) {
  int b = blockIdx.y, j = blockIdx.x;
  int t = threadIdx.x;
  if (j == 77) {
    if (t < 64) kb[((size_t)b * LPAD + 77) * 64 + t] = f2bf(null_kv[t]);
    else vt[((size_t)b * 64 + (t - 64)) * LPAD + Fj(77)] = f2bf(null_kv[64 + (t - 64)]);
    return;
  }
  if (j > 77) {
    int jj = LKV + (j - 78);
    if (t < 64) kb[((size_t)b * LPAD + jj) * 64 + t] = 0;
    else vt[((size_t)b * 64 + (t - 64)) * LPAD + Fj(jj)] = 0;
    return;
  }
  __shared__ float row[768];
  __shared__ float red[4];
  const float* src = ctx + (size_t)(b * 77 + j) * 768;
  float s = 0.f, s2 = 0.f;
  for (int k = t; k < 768; k += 128) {
    float v = src[k];
    row[k] = v; s += v; s2 += v * v;
  }
  for (int o = 32; o; o >>= 1) { s += __shfl_xor(s, o); s2 += __shfl_xor(s2, o); }
  if ((t & 63) == 0) { red[(t >> 6) * 2] = s; red[(t >> 6) * 2 + 1] = s2; }
  __syncthreads();
  float S = red[0] + red[2], S2 = red[1] + red[3];
  float mu = S * (1.0f / 768.0f);
  float rs = rsqrtf(S2 * (1.0f / 768.0f) - mu * mu + 1e-5f);
  __syncthreads();
  for (int k = t; k < 768; k += 128) row[k] = (row[k] - mu) * rs * g[k] + be[k];
  __syncthreads();
  const uint4* w4 = reinterpret_cast<const uint4*>(WctxT + (size_t)t * 768);
  float acc = 0.f;
  for (int k8 = 0; k8 < 96; k8++) {
    union { uint4 u; unsigned short s[8]; } wv;
    wv.u = w4[k8];
#pragma unroll
    for (int e = 0; e < 8; e++) acc += row[k8 * 8 + e] * bf2f(wv.s[e]);
  }
  acc += bctx[t];
  if (t < 64) kb[((size_t)b * LPAD + j) * 64 + t] = f2bf(acc);
  else vt[((size_t)b * 64 + (t - 64)) * LPAD + Fj(j)] = f2bf(acc);
}

// ---------------- MFMA GEMM: BM=128 BN=64 BK=64, global_load_lds + dbuf -----
template <int MODE>
__global__ __launch_bounds__(256, 1) void k_gemm(
    const unsigned short* __restrict__ A, const unsigned short* __restrict__ BT0,
    const unsigned short* __restrict__ BT1, unsigned short* __restrict__ out_q,
    unsigned short* __restrict__ out_k, unsigned short* __restrict__ out_vt,
    unsigned short* __restrict__ out_proj) {
  int m0 = blockIdx.x * 128, n0 = blockIdx.y * 64;
  int t = threadIdx.x;
  int lane = t & 63, w = t >> 6;
  int wm = w >> 1, wn = w & 1;
  int G = lane >> 4, li = lane & 15, li7 = lane & 7;
  __shared__ __align__(16) unsigned short Al[2][8192];  // 128 x 64
  __shared__ __align__(16) unsigned short Bl[2][4096];  // 64 x 64
  const unsigned short* BT = (MODE == 0 && n0 >= 512) ? BT1 : BT0;
  int bn0 = (MODE == 0 && n0 >= 512) ? n0 - 512 : n0;

  f32x4 zero = {0.f, 0.f, 0.f, 0.f};
  f32x4 acc[4][2];
#pragma unroll
  for (int a = 0; a < 4; a++)
#pragma unroll
    for (int c = 0; c < 2; c++) acc[a][c] = zero;

#define STAGE_AB(buf, k0)                                                              \
  {                                                                                    \
    _Pragma("unroll") for (int p = 0; p < 4; p++) {                                    \
      int gA = p * 256 + t;                                                            \
      int ra = gA >> 3;                                                                \
      int ca = ((gA & 7) ^ (ra & 7)) * 8;                                              \
      stage16(A + (size_t)(m0 + ra) * 512 + (k0) + ca, &Al[buf][(p * 256 + w * 64) * 8]); \
    }                                                                                  \
    _Pragma("unroll") for (int p = 0; p < 2; p++) {                                    \
      int gB = p * 256 + t;                                                            \
      int rb = gB >> 3;                                                                \
      int cb = ((gB & 7) ^ (rb & 7)) * 8;                                              \
      stage16(BT + (size_t)(bn0 + rb) * 512 + (k0) + cb, &Bl[buf][(p * 256 + w * 64) * 8]); \
    }                                                                                  \
  }

  STAGE_AB(0, 0)
  __syncthreads();

  for (int u = 0; u < 8; u++) {
    int cur = u & 1, nxt = cur ^ 1;
    if (u < 7) STAGE_AB(nxt, (u + 1) * 64)
    const char* Ac = (const char*)Al[cur];
    const char* Bc = (const char*)Bl[cur];
#pragma unroll
    for (int ks = 0; ks < 2; ks++) {
      bf16x8 af[4], bfr[2];
#pragma unroll
      for (int f = 0; f < 4; f++)
        af[f] = *reinterpret_cast<const bf16x8*>(
            Ac + ((((wm * 64 + f * 16 + li) * 8) + ((ks * 4 + G) ^ li7)) << 4));
#pragma unroll
      for (int f = 0; f < 2; f++)
        bfr[f] = *reinterpret_cast<const bf16x8*>(
            Bc + ((((wn * 32 + f * 16 + li) * 8) + ((ks * 4 + G) ^ li7)) << 4));
#pragma unroll
      for (int fm = 0; fm < 4; fm++)
#pragma unroll
        for (int fn = 0; fn < 2; fn++)
          acc[fm][fn] = MFMA(af[fm], bfr[fn], acc[fm][fn]);
    }
    __syncthreads();
  }
#undef STAGE_AB

#pragma unroll
  for (int fm = 0; fm < 4; fm++)
#pragma unroll
    for (int fn = 0; fn < 2; fn++)
#pragma unroll
      for (int r = 0; r < 4; r++) {
        int row = m0 + wm * 64 + fm * 16 + G * 4 + r;
        int col = n0 + wn * 32 + fn * 16 + li;
        float v = acc[fm][fn][r];
        if (MODE == 0) {
          int b = row / NSEQ, i = row - b * NSEQ;
          // q pre-scaled by 1/sqrt(dh) * log2(e): softmax runs in exp2 domain
          if (col < 512) out_q[(size_t)row * 512 + col] = f2bf(v * 0.18033688011112042f);
          else if (col < 576) out_k[((size_t)b * LPAD + 78 + i) * 64 + (col - 512)] = f2bf(v);
          else out_vt[((size_t)b * 64 + (col - 576)) * LPAD + Fj(78 + i)] = f2bf(v);
        } else {
          out_proj[(size_t)row * 512 + col] = f2bf(v);
        }
      }
}

// ---------------- flash attention: 3-way KV split, KVBLK=32, 16KB LDS -------
// 4-way split left a 9-blocks/CU supply with 4 resident -> 3rd residency
// round nearly empty (occ 35%). 3-way: 1728 blocks = 6.75/CU -> ~43% occ.
// sp packed into blockIdx.y (no integer division). Tiles 25/25/26.
__global__ __launch_bounds__(256, 4) void k_attn(
    const unsigned short* __restrict__ q, const unsigned short* __restrict__ kbuf,
    const unsigned short* __restrict__ vt, unsigned short* __restrict__ pO0,
    unsigned short* __restrict__ pO1, unsigned short* __restrict__ pO2,
    unsigned short* __restrict__ lp) {
  int it = blockIdx.x;
  int yy = blockIdx.y;
  int sp = yy >> 1, hh = yy & 1;
  int b = blockIdx.z;
  int i0 = it * 32;
  int t = threadIdx.x;
  int w = t >> 6, lane = t & 63;
  int G = lane >> 4, li = lane & 15, li7 = lane & 7;
  int swzV = (li ^ (li >> 2)) & 3;
  int h = hh * 4 + w;

  __shared__ __align__(16) unsigned short Kl[2][2048];  // 32 rows x 64 d (4KB)
  __shared__ __align__(16) unsigned short Vl[2][2048];  // 64 rows x 32 j (4KB)

  int rk = t >> 3;
  int ck = ((t & 7) ^ (rk & 7)) * 8;
  int rv = t >> 2;
  int cv = ((t & 3) ^ ((rv ^ (rv >> 2)) & 3)) * 8;

  const unsigned short* kbase = kbuf + (size_t)b * LPAD * 64;
  const unsigned short* vbase = vt + (size_t)b * 64 * LPAD;

  bf16x8 qf[2][2];
#pragma unroll
  for (int fi = 0; fi < 2; fi++)
#pragma unroll
    for (int ks = 0; ks < 2; ks++)
      qf[fi][ks] = *reinterpret_cast<const bf16x8*>(
          q + (size_t)(b * NSEQ + i0 + fi * 16 + li) * CDIM + h * 64 + ks * 32 + G * 8);

  int jt0 = sp * 25;                 // splits: [0,25) [25,50) [50,76)
  int nt = (sp == 2) ? 26 : 25;

  {
    int j0 = jt0 * 32;
    stage16(kbase + (size_t)(j0 + rk) * 64 + ck, &Kl[0][w * 512]);
    stage16(vbase + (size_t)rv * LPAD + j0 + cv, &Vl[0][w * 512]);
  }

  f32x4 zero = {0.f, 0.f, 0.f, 0.f};
  f32x4 OT[4][2];
#pragma unroll
  for (int fd = 0; fd < 4; fd++)
#pragma unroll
    for (int fi = 0; fi < 2; fi++) OT[fd][fi] = zero;
  float l_[2] = {0.f, 0.f};

  __syncthreads();

  for (int u = 0; u < nt; u++) {
    int jt = jt0 + u;
    int cur = u & 1, nxt = cur ^ 1;
    int j0 = jt * 32;
    if (u + 1 < nt) {
      int j1 = j0 + 32;
      stage16(kbase + (size_t)(j1 + rk) * 64 + ck, &Kl[nxt][w * 512]);
      stage16(vbase + (size_t)rv * LPAD + j1 + cv, &Vl[nxt][w * 512]);
    }
    const char* Kc = (const char*)Kl[cur];
    const char* Vc = (const char*)Vl[cur];

    f32x4 S[2][2];
#pragma unroll
    for (int fj = 0; fj < 2; fj++) { S[fj][0] = zero; S[fj][1] = zero; }
#pragma unroll
    for (int ks = 0; ks < 2; ks++) {
      bf16x8 kf[2];
#pragma unroll
      for (int fj = 0; fj < 2; fj++)
        kf[fj] = *reinterpret_cast<const bf16x8*>(
            Kc + ((((fj * 16 + li) * 8) + ((ks * 4 + G) ^ li7)) << 4));
#pragma unroll
      for (int fj = 0; fj < 2; fj++)
#pragma unroll
        for (int fi = 0; fi < 2; fi++)
          S[fj][fi] = MFMA(kf[fj], qf[fi][ks], S[fj][fi]);
    }
    if (j0 + 32 > LKV) {
#pragma unroll
      for (int fj = 0; fj < 2; fj++)
#pragma unroll
        for (int r = 0; r < 4; r++) {
          int jg = j0 + fj * 16 + G * 4 + r;
          if (jg >= LKV) { S[fj][0][r] = -1e30f; S[fj][1][r] = -1e30f; }
        }
    }
    bf16x8 pf[2];
#pragma unroll
    for (int fi = 0; fi < 2; fi++) {
      float e[2][4];
#pragma unroll
      for (int fj = 0; fj < 2; fj++)
#pragma unroll
        for (int r = 0; r < 4; r++) e[fj][r] = __builtin_exp2f(S[fj][fi][r]);
      float s0 = (e[0][0] + e[0][1]) + (e[0][2] + e[0][3]);
      float s1 = (e[1][0] + e[1][1]) + (e[1][2] + e[1][3]);
      l_[fi] += s0 + s1;
      union { unsigned int w4[4]; bf16x8 v; } u2;
#pragma unroll
      for (int m = 0; m < 4; m++) u2.w4[m] = cvtpk(e[0][m], e[1][m]);
      pf[fi] = u2.v;
    }
#pragma unroll
    for (int fd = 0; fd < 4; fd++) {
      bf16x8 uv = *reinterpret_cast<const bf16x8*>(
          Vc + (((fd * 16 + li) * 4 + (G ^ swzV)) << 4));
#pragma unroll
      for (int fi = 0; fi < 2; fi++) OT[fd][fi] = MFMA(uv, pf[fi], OT[fd][fi]);
    }
    __syncthreads();
  }

  unsigned short* pO = (sp == 0) ? pO0 : (sp == 1) ? pO1 : pO2;
#pragma unroll
  for (int fi = 0; fi < 2; fi++) {
    l_[fi] += __shfl_xor(l_[fi], 16);
    l_[fi] += __shfl_xor(l_[fi], 32);
    int row = b * NSEQ + i0 + fi * 16 + li;
    if (G == 0) lp[sp * LPSZ + row * 8 + h] = f2bf(l_[fi]);
#pragma unroll
    for (int fd = 0; fd < 4; fd++) {
      union { unsigned int w2[2]; uint2 u2; } pk;
      pk.w2[0] = cvtpk(OT[fd][fi][0], OT[fd][fi][1]);
      pk.w2[1] = cvtpk(OT[fd][fi][2], OT[fd][fi][3]);
      *reinterpret_cast<uint2*>(pO + (size_t)row * CDIM + h * 64 + fd * 16 + G * 4) = pk.u2;
    }
  }
}

// ---------------- merge the three KV-split partials ----------------
__global__ void k_merge(unsigned short* __restrict__ pO0,
                        const unsigned short* __restrict__ pO1,
                        const unsigned short* __restrict__ pO2,
                        const unsigned short* __restrict__ lp) {
  int c = blockIdx.x * 256 + threadIdx.x;
  size_t base = (size_t)c * 8;
  int row = (int)(base >> 9);
  int h = (int)((base >> 6) & 7);
  int li = row * 8 + h;
  float l = bf2f(lp[li]) + bf2f(lp[LPSZ + li]) + bf2f(lp[2 * LPSZ + li]);
  float inv = 1.0f / l;
  union { uint4 u; unsigned short s[8]; } a0, a1, a2, o;
  a0.u = *reinterpret_cast<const uint4*>(pO0 + base);
  a1.u = *reinterpret_cast<const uint4*>(pO1 + base);
  a2.u = *reinterpret_cast<const uint4*>(pO2 + base);
  unsigned int* ow = reinterpret_cast<unsigned int*>(&o.u);
#pragma unroll
  for (int m = 0; m < 4; m++) {
    float v0 = (bf2f(a0.s[2 * m]) + bf2f(a1.s[2 * m]) + bf2f(a2.s[2 * m])) * inv;
    float v1 = (bf2f(a0.s[2 * m + 1]) + bf2f(a1.s[2 * m + 1]) + bf2f(a2.s[2 * m + 1])) * inv;
    ow[m] = cvtpk(v0, v1);
  }
  *reinterpret_cast<uint4*>(pO0 + base) = o.u;
}

// ---------------- per-row LN stats of proj (bf16, coalesced) ----------------
__global__ void k_stats(const unsigned short* __restrict__ proj, float* __restrict__ musig) {
  int w = threadIdx.x >> 6, lane = threadIdx.x & 63;
  int row = blockIdx.x * 4 + w;
  union { uint4 u; unsigned short s[8]; } a;
  a.u = *reinterpret_cast<const uint4*>(proj + (size_t)row * CDIM + lane * 8);
  float s = 0.f, s2 = 0.f;
#pragma unroll
  for (int m = 0; m < 8; m++) {
    float v = bf2f(a.s[m]);
    s += v; s2 += v * v;
  }
  for (int o = 32; o; o >>= 1) { s += __shfl_xor(s, o); s2 += __shfl_xor(s2, o); }
  if (lane == 0) {
    float mu = s * (1.0f / 512.0f);
    float var = s2 * (1.0f / 512.0f) - mu * mu;
    musig[row] = mu;
    musig[4 * NSEQ + row] = rsqrtf(var + 1e-5f);
  }
}

// ---------------- final LN + residual, LDS-transposed, fully coalesced ------
__global__ void k_final2(const unsigned short* __restrict__ proj, const float* __restrict__ musig,
                         const float* __restrict__ g, const float* __restrict__ x,
                         float* __restrict__ y) {
  int i0 = blockIdx.x * 32, c0 = blockIdx.y * 64, b = blockIdx.z;
  int t = threadIdx.x;
  __shared__ float lds[32][65];
  {
    int il = t >> 3, cB = (t & 7) * 8;
    union { uint4 u; unsigned short s[8]; } a;
    a.u = *reinterpret_cast<const uint4*>(proj + (size_t)(b * NSEQ + i0 + il) * CDIM + c0 + cB);
#pragma unroll
    for (int m = 0; m < 8; m++) lds[il][cB + m] = bf2f(a.s[m]);
  }
  __syncthreads();
  int ii = t & 31, cg = t >> 5;
  float mu = musig[b * NSEQ + i0 + ii];
  float rs = musig[4 * NSEQ + b * NSEQ + i0 + ii];
  const float* xb = x + (size_t)b * CDIM * NSEQ;
  float* yb = y + (size_t)b * CDIM * NSEQ;
#pragma unroll
  for (int cc = 0; cc < 8; cc++) {
    int cl = cg * 8 + cc;
    int c = c0 + cl;
    float v = lds[ii][cl];
    yb[(size_t)c * NSEQ + i0 + ii] = xb[(size_t)c * NSEQ + i0 + ii] + (v - mu) * rs * g[c];
  }
}

extern "C" void kernel_launch(void* const* d_in, const int* in_sizes, int n_in,
                              void* d_out, int out_size, void* d_ws, size_t ws_size,
                              hipStream_t stream) {
  const float* x       = (const float*)d_in[0];
  const float* context = (const float*)d_in[1];
  const float* ngamma  = (const float*)d_in[2];
  const float* null_kv = (const float*)d_in[3];
  const float* Wq      = (const float*)d_in[4];
  const float* Wkv     = (const float*)d_in[5];
  const float* clng    = (const float*)d_in[6];
  const float* clnb    = (const float*)d_in[7];
  const float* Wctx    = (const float*)d_in[8];
  const float* bctx    = (const float*)d_in[9];
  const float* Wout    = (const float*)d_in[10];
  const float* olng    = (const float*)d_in[11];
  float* y = (float*)d_out;
  char* ws = (char*)d_ws;

  unsigned short* xn    = (unsigned short*)(ws);              // 9437184 B (pO1 during attn)
  unsigned short* qb    = (unsigned short*)(ws + 9437184);    // 9437184 B
  unsigned short* proj  = (unsigned short*)(ws);              // bf16, aliases xn (dead by then)
  unsigned short* aoutb = (unsigned short*)(ws + 18874368);   // 9437184 B (pO0 -> merged)
  float* musig          = (float*)(ws + 18874368);            // aliases aoutb (dead after gemm1)
  unsigned short* kb    = (unsigned short*)(ws + 28311552);   // 1245184 B
  unsigned short* vtb   = (unsigned short*)(ws + 29556736);   // 1245184 B
  unsigned short* WqT   = (unsigned short*)(ws + 30801920);   // 524288 B
  unsigned short* WkvT  = (unsigned short*)(ws + 31326208);   // 131072 B
  unsigned short* WctxT = (unsigned short*)(ws + 31457280);   // 196608 B
  unsigned short* WoutT = (unsigned short*)(ws + 31653888);   // 524288 B
  // bf16 l-partials: 3 x 73728 x 2B = 442368 B, overlay WqT (dead after gemm0)
  unsigned short* lpart = (unsigned short*)(ws + 30801920);
  // partial 2 lives in d_out (first 9437184 B); k_final2 fully rewrites y.
  unsigned short* pO2   = (unsigned short*)d_out;

  k_prep<<<dim3(672), dim3(256), 0, stream>>>(Wq, Wkv, Wctx, Wout, WqT, WkvT, WctxT, WoutT);
  k_ln1<<<dim3(72, 4), dim3(256), 0, stream>>>(x, ngamma, xn);
  k_ctx<<<dim3(128, 4), dim3(128), 0, stream>>>(context, clng, clnb, WctxT, bctx, null_kv, kb, vtb);
  k_gemm<0><<<dim3(72, 10), dim3(256), 0, stream>>>(xn, WqT, WkvT, qb, kb, vtb, nullptr);
  k_attn<<<dim3(72, 6, 4), dim3(256), 0, stream>>>(qb, kb, vtb, aoutb, xn, pO2, lpart);
  k_merge<<<dim3(2304), dim3(256), 0, stream>>>(aoutb, xn, pO2, lpart);
  k_gemm<1><<<dim3(72, 8), dim3(256), 0, stream>>>(aoutb, WoutT, nullptr, nullptr, nullptr, nullptr, proj);
  k_stats<<<dim3(2304), dim3(256), 0, stream>>>(proj, musig);
  k_final2<<<dim3(72, 8, 4), dim3(256), 0, stream>>>(proj, musig, olng, x, y);
}